// Round 1
// baseline (614.136 us; speedup 1.0000x reference)
//
#include <hip/hip_runtime.h>
#include <hip/hip_bf16.h>

typedef unsigned short u16;
using f32x4  = __attribute__((ext_vector_type(4))) float;
using bf16x8 = __attribute__((ext_vector_type(8))) short;

#define N_B 4
#define N_S 4096
#define N_C 1280
#define N_DC 2048
#define N_H 20
#define N_D 64

__device__ __forceinline__ u16 f2b(float f) {
  union { float f; unsigned u; } x; x.f = f;
  return (u16)((x.u + 0x7fffu + ((x.u >> 16) & 1u)) >> 16);
}

// ---------- weight transpose + bf16 convert: src (K x N) f32 -> dst (N x K) bf16
__global__ void k_transpose(const float* __restrict__ src, u16* __restrict__ dst,
                            int K, int N) {
  __shared__ float tl[32][33];
  int n0 = blockIdx.x * 32, k0 = blockIdx.y * 32;
  int tx = threadIdx.x, ty = threadIdx.y;   // 32 x 8
#pragma unroll
  for (int j = 0; j < 32; j += 8)
    tl[ty + j][tx] = src[(size_t)(k0 + ty + j) * N + (n0 + tx)];
  __syncthreads();
#pragma unroll
  for (int j = 0; j < 32; j += 8)
    dst[(size_t)(n0 + ty + j) * K + (k0 + tx)] = f2b(tl[tx][ty + j]);
}

// ---------- pack encoder rows into per-segment bf16 buffers
__global__ void k_encpack(const float* __restrict__ enc, u16* __restrict__ txt,
                          u16* __restrict__ img, u16* __restrict__ lbl) {
  int row = blockIdx.x;          // b*85 + l
  int b = row / 85, l = row % 85;
  const float* s = enc + (size_t)row * N_DC;
  u16* d;
  if (l < 77)      d = txt + (size_t)(b * 77 + l) * N_DC;
  else if (l < 81) d = img + (size_t)(b * 4 + (l - 77)) * N_DC;
  else             d = lbl + (size_t)(b * 4 + (l - 81)) * N_DC;
  for (int i = threadIdx.x; i < N_DC; i += 256) d[i] = f2b(s[i]);
}

// ---------- GEMM: C[M x N] = A[M x K] * Bt[N x K]^T   (bf16 MFMA, f32 acc)
// BM=BN=128, BK=64, 256 threads = 4 waves in 2x2, wave tile 64x64.
// EPI: 0 = bf16 store, 1 = bf16 store * scale, 2 = f32 store + bias + resid
#define LDSTR 72   // padded LDS row stride in bf16 (144 B)

template<int AF32, int EPI>
__global__ __launch_bounds__(256, 2)
void gemm_kern(const void* __restrict__ Av, const u16* __restrict__ Bt,
               void* __restrict__ Cv, int M, int N, int K, float scale,
               const float* __restrict__ bias, const float* __restrict__ resid) {
  __shared__ u16 Alds[128 * LDSTR];
  __shared__ u16 Blds[128 * LDSTR];
  int nt = N >> 7;
  int bm = blockIdx.x / nt, bn = blockIdx.x % nt;
  int t = threadIdx.x, lane = t & 63, w = t >> 6;
  int wm = w >> 1, wn = w & 1;
  f32x4 acc[4][4] = {};
  const float* Af = (const float*)Av;
  const u16*   Ab = (const u16*)Av;

  for (int k0 = 0; k0 < K; k0 += 64) {
#pragma unroll
    for (int i = 0; i < 4; i++) {
      int cid = t + i * 256;
      int r = cid >> 3, c8 = cid & 7;
      int ra = bm * 128 + r; if (ra >= M) ra = M - 1;
      alignas(16) u16 tmp[8];
      if constexpr (AF32) {
        const float* p = Af + (size_t)ra * K + k0 + c8 * 8;
        float4 v0 = *(const float4*)p;
        float4 v1 = *(const float4*)(p + 4);
        tmp[0] = f2b(v0.x); tmp[1] = f2b(v0.y); tmp[2] = f2b(v0.z); tmp[3] = f2b(v0.w);
        tmp[4] = f2b(v1.x); tmp[5] = f2b(v1.y); tmp[6] = f2b(v1.z); tmp[7] = f2b(v1.w);
      } else {
        *(uint4*)tmp = *(const uint4*)(Ab + (size_t)ra * K + k0 + c8 * 8);
      }
      *(uint4*)&Alds[r * LDSTR + c8 * 8] = *(uint4*)tmp;
      int rb = bn * 128 + r;
      *(uint4*)&Blds[r * LDSTR + c8 * 8] = *(const uint4*)(Bt + (size_t)rb * K + k0 + c8 * 8);
    }
    __syncthreads();
#pragma unroll
    for (int ks = 0; ks < 2; ks++) {
      bf16x8 afr[4], bfr[4];
#pragma unroll
      for (int m = 0; m < 4; m++) {
        int row = wm * 64 + m * 16 + (lane & 15);
        afr[m] = *(bf16x8*)&Alds[row * LDSTR + ks * 32 + (lane >> 4) * 8];
      }
#pragma unroll
      for (int n = 0; n < 4; n++) {
        int row = wn * 64 + n * 16 + (lane & 15);
        bfr[n] = *(bf16x8*)&Blds[row * LDSTR + ks * 32 + (lane >> 4) * 8];
      }
#pragma unroll
      for (int m = 0; m < 4; m++)
#pragma unroll
        for (int n = 0; n < 4; n++)
          acc[m][n] = __builtin_amdgcn_mfma_f32_16x16x32_bf16(afr[m], bfr[n], acc[m][n], 0, 0, 0);
    }
    __syncthreads();
  }

#pragma unroll
  for (int m = 0; m < 4; m++) {
    int row = bm * 128 + wm * 64 + m * 16 + ((lane >> 4) << 2);
#pragma unroll
    for (int n = 0; n < 4; n++) {
      int col = bn * 128 + wn * 64 + n * 16 + (lane & 15);
#pragma unroll
      for (int j = 0; j < 4; j++) {
        int r = row + j;
        if (r >= M) continue;
        float v = acc[m][n][j];
        if constexpr (EPI == 0)      ((u16*)Cv)[(size_t)r * N + col] = f2b(v);
        else if constexpr (EPI == 1) ((u16*)Cv)[(size_t)r * N + col] = f2b(v * scale);
        else ((float*)Cv)[(size_t)r * N + col] = v + bias[col] + resid[(size_t)r * N + col];
      }
    }
  }
}

// ---------- fused attention: per (b,h,128-row s-tile), 85 keys in 3 softmax segments
// key slots: text 0..76, (77..79 zero), img 80..83, lbl 84..87, (88..95 zero)
#define QSTR 72    // Q/K LDS stride (bf16)
#define PSTR 104   // P/Vt LDS stride (bf16)

__global__ __launch_bounds__(256, 2)
void attn_kern(const u16* __restrict__ q,
               const u16* __restrict__ ktxt, const u16* __restrict__ vtxt,
               const u16* __restrict__ kimg, const u16* __restrict__ vimg,
               const u16* __restrict__ klbl, const u16* __restrict__ vlbl,
               u16* __restrict__ outa) {
  __shared__ __align__(16) char smem[45568];
  u16* Qs = (u16*)smem;                 // 128 x QSTR = 18432 B
  u16* Ks = (u16*)(smem + 18432);       // 96  x QSTR = 13824 B
  u16* Ps = (u16*)smem;                 // 128 x PSTR = 26624 B (overlaps Q/K)
  u16* Vt = (u16*)(smem + 32256);       // 64  x PSTR = 13312 B

  int st = blockIdx.x, h = blockIdx.y, b = blockIdx.z;
  int t = threadIdx.x, lane = t & 63, w = t >> 6;
  int s0 = st * 128;
  int c = lane & 15, g = lane >> 4;

  // zero K + Vt regions (27136 B starting at 18432)
  for (int i = t; i < 27136 / 16; i += 256)
    ((uint4*)(smem + 18432))[i] = make_uint4(0, 0, 0, 0);
  // stage Q (disjoint region, no sync needed yet)
#pragma unroll
  for (int i = 0; i < 4; i++) {
    int cid = t + i * 256; int r = cid >> 3, c8 = cid & 7;
    *(uint4*)&Qs[r * QSTR + c8 * 8] =
        *(const uint4*)(q + (size_t)(b * N_S + s0 + r) * N_C + h * N_D + c8 * 8);
  }
  __syncthreads();
  // stage K rows
  for (int cid = t; cid < 680; cid += 256) {
    int l = cid >> 3, c8 = cid & 7;
    const u16* p;
    if (l < 77)      p = ktxt + (size_t)(b * 77 + l) * N_C + h * N_D + c8 * 8;
    else if (l < 81) p = kimg + (size_t)(b * 4 + l - 77) * N_C + h * N_D + c8 * 8;
    else             p = klbl + (size_t)(b * 4 + l - 81) * N_C + h * N_D + c8 * 8;
    int row = (l < 77) ? l : l + 3;
    *(uint4*)&Ks[row * QSTR + c8 * 8] = *(const uint4*)p;
  }
  // stage V transposed: Vt[d][slot]
  for (int e = t; e < 85 * 64; e += 256) {
    int l = e >> 6, d = e & 63;
    const u16* p;
    if (l < 77)      p = vtxt + (size_t)(b * 77 + l) * N_C + h * N_D + d;
    else if (l < 81) p = vimg + (size_t)(b * 4 + l - 77) * N_C + h * N_D + d;
    else             p = vlbl + (size_t)(b * 4 + l - 81) * N_C + h * N_D + d;
    int slot = (l < 77) ? l : l + 3;
    Vt[d * PSTR + slot] = *p;
  }
  __syncthreads();

  // scores: wave w handles rows w*32..w*32+31, all 96 key slots
  f32x4 sacc[2][6] = {};
#pragma unroll
  for (int ks = 0; ks < 2; ks++) {
    bf16x8 aq[2], bk[6];
#pragma unroll
    for (int m = 0; m < 2; m++) {
      int row = w * 32 + m * 16 + c;
      aq[m] = *(bf16x8*)&Qs[row * QSTR + ks * 32 + g * 8];
    }
#pragma unroll
    for (int n = 0; n < 6; n++) {
      int row = n * 16 + c;
      bk[n] = *(bf16x8*)&Ks[row * QSTR + ks * 32 + g * 8];
    }
#pragma unroll
    for (int m = 0; m < 2; m++)
#pragma unroll
      for (int n = 0; n < 6; n++)
        sacc[m][n] = __builtin_amdgcn_mfma_f32_16x16x32_bf16(aq[m], bk[n], sacc[m][n], 0, 0, 0);
  }
  __syncthreads();   // everyone done reading Q/K; P may overwrite

  const float NEG = -1e30f;
#pragma unroll
  for (int m = 0; m < 2; m++) {
#pragma unroll
    for (int j = 0; j < 4; j++) {
      // text segment: cols 0..76 (frags 0..4)
      float tmax = NEG;
#pragma unroll
      for (int n = 0; n < 5; n++)
        if (n * 16 + c < 77) tmax = fmaxf(tmax, sacc[m][n][j]);
#pragma unroll
      for (int off = 1; off < 16; off <<= 1) tmax = fmaxf(tmax, __shfl_xor(tmax, off));
      float pv[5], tsum = 0.f;
#pragma unroll
      for (int n = 0; n < 5; n++) {
        float v = (n * 16 + c < 77) ? __expf(sacc[m][n][j] - tmax) : 0.f;
        pv[n] = v; tsum += v;
      }
#pragma unroll
      for (int off = 1; off < 16; off <<= 1) tsum += __shfl_xor(tsum, off);
      // img (frag5 lanes 0..3), lbl (frag5 lanes 4..7)
      float v5 = sacc[m][5][j];
      float imax = (c < 4) ? v5 : NEG;
#pragma unroll
      for (int off = 1; off < 16; off <<= 1) imax = fmaxf(imax, __shfl_xor(imax, off));
      float ie = (c < 4) ? __expf(v5 - imax) : 0.f, isum = ie;
#pragma unroll
      for (int off = 1; off < 16; off <<= 1) isum += __shfl_xor(isum, off);
      float lmax = (c >= 4 && c < 8) ? v5 : NEG;
#pragma unroll
      for (int off = 1; off < 16; off <<= 1) lmax = fmaxf(lmax, __shfl_xor(lmax, off));
      float le = (c >= 4 && c < 8) ? __expf(v5 - lmax) : 0.f, lsum = le;
#pragma unroll
      for (int off = 1; off < 16; off <<= 1) lsum += __shfl_xor(lsum, off);

      float rt = 1.f / tsum;
      float p5 = (c < 4) ? ie / isum : ((c < 8) ? le / lsum : 0.f);
      int rowl = w * 32 + m * 16 + g * 4 + j;
#pragma unroll
      for (int n = 0; n < 5; n++)
        Ps[rowl * PSTR + n * 16 + c] = f2b(pv[n] * rt);
      Ps[rowl * PSTR + 80 + c] = f2b(p5);
    }
  }
  __syncthreads();

  // PV: out[row][d] = sum_slot P[row][slot] * V[slot][d]
  f32x4 oacc[2][4] = {};
#pragma unroll
  for (int ks = 0; ks < 3; ks++) {
    bf16x8 ap[2], bv[4];
#pragma unroll
    for (int m = 0; m < 2; m++) {
      int row = w * 32 + m * 16 + c;
      ap[m] = *(bf16x8*)&Ps[row * PSTR + ks * 32 + g * 8];
    }
#pragma unroll
    for (int n = 0; n < 4; n++) {
      int row = n * 16 + c;   // d index
      bv[n] = *(bf16x8*)&Vt[row * PSTR + ks * 32 + g * 8];
    }
#pragma unroll
    for (int m = 0; m < 2; m++)
#pragma unroll
      for (int n = 0; n < 4; n++)
        oacc[m][n] = __builtin_amdgcn_mfma_f32_16x16x32_bf16(ap[m], bv[n], oacc[m][n], 0, 0, 0);
  }

#pragma unroll
  for (int m = 0; m < 2; m++) {
    int rbase = w * 32 + m * 16 + g * 4;
#pragma unroll
    for (int n = 0; n < 4; n++) {
      int d = n * 16 + c;
#pragma unroll
      for (int j = 0; j < 4; j++) {
        int s = s0 + rbase + j;
        outa[(size_t)(b * N_S + s) * N_C + h * N_D + d] = f2b(oacc[m][n][j]);
      }
    }
  }
}

extern "C" void kernel_launch(void* const* d_in, const int* in_sizes, int n_in,
                              void* d_out, int out_size, void* d_ws, size_t ws_size,
                              hipStream_t stream) {
  const float* hs   = (const float*)d_in[0];
  const float* enc  = (const float*)d_in[1];
  const float* Wq   = (const float*)d_in[2];
  const float* Wk   = (const float*)d_in[3];
  const float* Wv   = (const float*)d_in[4];
  const float* Wkip = (const float*)d_in[5];
  const float* Wvip = (const float*)d_in[6];
  const float* Wklb = (const float*)d_in[7];
  const float* Wvlb = (const float*)d_in[8];
  const float* Wo   = (const float*)d_in[9];
  const float* bo   = (const float*)d_in[10];

  if (ws_size < 83087360u) return;
  char* ws = (char*)d_ws;
  u16* wq_t   = (u16*)(ws + 0);
  u16* wo_t   = (u16*)(ws + 3276800);
  u16* wk_t   = (u16*)(ws + 6553600);
  u16* wv_t   = (u16*)(ws + 11796480);
  u16* wkip_t = (u16*)(ws + 17039360);
  u16* wvip_t = (u16*)(ws + 22282240);
  u16* wklb_t = (u16*)(ws + 27525120);
  u16* wvlb_t = (u16*)(ws + 32768000);
  u16* etxt   = (u16*)(ws + 38010880);
  u16* eimg   = (u16*)(ws + 39272448);
  u16* elbl   = (u16*)(ws + 39337984);
  u16* ktxt   = (u16*)(ws + 39403520);
  u16* vtxt   = (u16*)(ws + 40192000);
  u16* kimg   = (u16*)(ws + 40980480);
  u16* vimg   = (u16*)(ws + 41021440);
  u16* klbl   = (u16*)(ws + 41062400);
  u16* vlbl   = (u16*)(ws + 41103360);
  u16* attn   = (u16*)(ws + 41144320);
  u16* qbuf   = (u16*)d_out;   // q (bf16) lives in d_out's lower half until O-proj

  dim3 tb(32, 8);
  k_transpose<<<dim3(40, 40), tb, 0, stream>>>(Wq,   wq_t,   1280, 1280);
  k_transpose<<<dim3(40, 40), tb, 0, stream>>>(Wo,   wo_t,   1280, 1280);
  k_transpose<<<dim3(40, 64), tb, 0, stream>>>(Wk,   wk_t,   2048, 1280);
  k_transpose<<<dim3(40, 64), tb, 0, stream>>>(Wv,   wv_t,   2048, 1280);
  k_transpose<<<dim3(40, 64), tb, 0, stream>>>(Wkip, wkip_t, 2048, 1280);
  k_transpose<<<dim3(40, 64), tb, 0, stream>>>(Wvip, wvip_t, 2048, 1280);
  k_transpose<<<dim3(40, 64), tb, 0, stream>>>(Wklb, wklb_t, 2048, 1280);
  k_transpose<<<dim3(40, 64), tb, 0, stream>>>(Wvlb, wvlb_t, 2048, 1280);
  k_encpack<<<340, 256, 0, stream>>>(enc, etxt, eimg, elbl);

  // Q = hs @ Wq, scaled by D^-0.5 (exact power of 2), bf16 out
  gemm_kern<1, 1><<<1280, 256, 0, stream>>>(hs, wq_t, qbuf, 16384, 1280, 1280,
                                            0.125f, nullptr, nullptr);
  // KV projections
  gemm_kern<0, 0><<<30, 256, 0, stream>>>(etxt, wk_t,   ktxt, 308, 1280, 2048, 1.f, nullptr, nullptr);
  gemm_kern<0, 0><<<30, 256, 0, stream>>>(etxt, wv_t,   vtxt, 308, 1280, 2048, 1.f, nullptr, nullptr);
  gemm_kern<0, 0><<<10, 256, 0, stream>>>(eimg, wkip_t, kimg, 16,  1280, 2048, 1.f, nullptr, nullptr);
  gemm_kern<0, 0><<<10, 256, 0, stream>>>(eimg, wvip_t, vimg, 16,  1280, 2048, 1.f, nullptr, nullptr);
  gemm_kern<0, 0><<<10, 256, 0, stream>>>(elbl, wklb_t, klbl, 16,  1280, 2048, 1.f, nullptr, nullptr);
  gemm_kern<0, 0><<<10, 256, 0, stream>>>(elbl, wvlb_t, vlbl, 16,  1280, 2048, 1.f, nullptr, nullptr);

  attn_kern<<<dim3(32, N_H, N_B), 256, 0, stream>>>(qbuf, ktxt, vtxt, kimg, vimg,
                                                    klbl, vlbl, attn);
  // out = attn @ Wo + bo + hs
  gemm_kern<0, 2><<<1280, 256, 0, stream>>>(attn, wo_t, d_out, 16384, 1280, 1280,
                                            1.f, bo, hs);
}

// Round 2
// 341.753 us; speedup vs baseline: 1.7970x; 1.7970x over previous
//
#include <hip/hip_runtime.h>
#include <hip/hip_bf16.h>

typedef unsigned short u16;
using f32x4  = __attribute__((ext_vector_type(4))) float;
using bf16x8 = __attribute__((ext_vector_type(8))) short;

#define N_B 4
#define N_S 4096
#define N_C 1280
#define N_DC 2048
#define N_H 20
#define N_D 64

__device__ __forceinline__ u16 f2b(float f) {
  union { float f; unsigned u; } x; x.f = f;
  return (u16)((x.u + 0x7fffu + ((x.u >> 16) & 1u)) >> 16);
}

__device__ __forceinline__ void gld16(const u16* g, u16* l) {
  __builtin_amdgcn_global_load_lds(
      (const __attribute__((address_space(1))) unsigned int*)(g),
      (__attribute__((address_space(3))) unsigned int*)(l), 16, 0, 0);
}

// ---------- hs f32 -> bf16 (8 elems/thread, grid-stride)
__global__ void k_cvt(const float* __restrict__ src, u16* __restrict__ dst, int n8) {
  for (int i = blockIdx.x * 256 + threadIdx.x; i < n8; i += gridDim.x * 256) {
    const float4 v0 = *(const float4*)(src + (size_t)i * 8);
    const float4 v1 = *(const float4*)(src + (size_t)i * 8 + 4);
    alignas(16) u16 t[8];
    t[0] = f2b(v0.x); t[1] = f2b(v0.y); t[2] = f2b(v0.z); t[3] = f2b(v0.w);
    t[4] = f2b(v1.x); t[5] = f2b(v1.y); t[6] = f2b(v1.z); t[7] = f2b(v1.w);
    *(uint4*)(dst + (size_t)i * 8) = *(uint4*)t;
  }
}

// ---------- batched weight transpose + bf16: 8 weights in one launch
struct TPargs { const float* s[8]; u16* d[8]; int K[8]; };

__global__ void k_transpose8(TPargs a) {
  int z = blockIdx.z;
  const float* __restrict__ src = a.s[z];
  u16* __restrict__ dst = a.d[z];
  int K = a.K[z];
  int k0 = blockIdx.y * 32;
  if (k0 >= K) return;
  __shared__ float tl[32][33];
  int n0 = blockIdx.x * 32;
  int tx = threadIdx.x, ty = threadIdx.y;   // 32 x 8
#pragma unroll
  for (int j = 0; j < 32; j += 8)
    tl[ty + j][tx] = src[(size_t)(k0 + ty + j) * N_C + (n0 + tx)];
  __syncthreads();
#pragma unroll
  for (int j = 0; j < 32; j += 8)
    dst[(size_t)(n0 + ty + j) * K + (k0 + tx)] = f2b(tl[tx][ty + j]);
}

// ---------- pack encoder rows into per-segment bf16 buffers
__global__ void k_encpack(const float* __restrict__ enc, u16* __restrict__ txt,
                          u16* __restrict__ img, u16* __restrict__ lbl) {
  int row = blockIdx.x;          // b*85 + l
  int b = row / 85, l = row % 85;
  const float* s = enc + (size_t)row * N_DC;
  u16* d;
  if (l < 77)      d = txt + (size_t)(b * 77 + l) * N_DC;
  else if (l < 81) d = img + (size_t)(b * 4 + (l - 77)) * N_DC;
  else             d = lbl + (size_t)(b * 4 + (l - 81)) * N_DC;
  for (int i = threadIdx.x; i < N_DC; i += 256) d[i] = f2b(s[i]);
}

// ---------- m97-structure GEMM core: C[M x N] = A[M x K](bf16) * Bt[N x K]^T
// BM=BN=128, BK=64, 256 threads = 4 waves 2x2, wave tile 64x64.
// Staging via global_load_lds width=16 into linear [128][64] LDS.
// EPI: 0 = bf16 store, 1 = bf16 store * scale, 2 = f32 store + bias + resid
template<int EPI>
__device__ __forceinline__ void gemm_core(
    const u16* __restrict__ A, const u16* __restrict__ Bt, void* __restrict__ Cv,
    int M, int N, int K, int bm, int bn, float scale,
    const float* __restrict__ bias, const float* __restrict__ resid,
    u16* Alds, u16* Blds) {
  int t = threadIdx.x, lane = t & 63, w = t >> 6;
  int wm = w >> 1, wn = w & 1;
  f32x4 acc[4][4] = {};
  int c8 = lane & 7;
  int rsub = lane >> 3;            // 0..7

  for (int k0 = 0; k0 < K; k0 += 64) {
    if (k0) __syncthreads();
#pragma unroll
    for (int i = 0; i < 4; i++) {
      int rloc = w * 32 + i * 8;
      int ra = bm * 128 + rloc + rsub; if (ra >= M) ra = M - 1;
      int rb = bn * 128 + rloc + rsub;
      gld16(A  + (size_t)ra * K + k0 + c8 * 8, &Alds[rloc * 64]);
      gld16(Bt + (size_t)rb * K + k0 + c8 * 8, &Blds[rloc * 64]);
    }
    __syncthreads();
#pragma unroll
    for (int ks = 0; ks < 2; ks++) {
      bf16x8 afr[4], bfr[4];
#pragma unroll
      for (int m = 0; m < 4; m++)
        afr[m] = *(bf16x8*)&Alds[(wm * 64 + m * 16 + (lane & 15)) * 64 + ks * 32 + (lane >> 4) * 8];
#pragma unroll
      for (int n = 0; n < 4; n++)
        bfr[n] = *(bf16x8*)&Blds[(wn * 64 + n * 16 + (lane & 15)) * 64 + ks * 32 + (lane >> 4) * 8];
#pragma unroll
      for (int m = 0; m < 4; m++)
#pragma unroll
        for (int n = 0; n < 4; n++)
          acc[m][n] = __builtin_amdgcn_mfma_f32_16x16x32_bf16(afr[m], bfr[n], acc[m][n], 0, 0, 0);
    }
  }

#pragma unroll
  for (int m = 0; m < 4; m++) {
    int row = bm * 128 + wm * 64 + m * 16 + ((lane >> 4) << 2);
#pragma unroll
    for (int n = 0; n < 4; n++) {
      int col = bn * 128 + wn * 64 + n * 16 + (lane & 15);
#pragma unroll
      for (int j = 0; j < 4; j++) {
        int r = row + j;
        if (r >= M) continue;
        float v = acc[m][n][j];
        if constexpr (EPI == 0)      ((u16*)Cv)[(size_t)r * N + col] = f2b(v);
        else if constexpr (EPI == 1) ((u16*)Cv)[(size_t)r * N + col] = f2b(v * scale);
        else ((float*)Cv)[(size_t)r * N + col] = v + bias[col] + resid[(size_t)r * N + col];
      }
    }
  }
}

template<int EPI>
__global__ __launch_bounds__(256, 2)
void gemm97(const u16* __restrict__ A, const u16* __restrict__ Bt, void* __restrict__ Cv,
            int M, int N, int K, float scale,
            const float* __restrict__ bias, const float* __restrict__ resid) {
  __shared__ u16 Alds[128 * 64];
  __shared__ u16 Blds[128 * 64];
  int nt = N >> 7;
  int nwg = gridDim.x;
  int bid = blockIdx.x;
  int swz = ((nwg & 7) == 0) ? ((bid & 7) * (nwg >> 3) + (bid >> 3)) : bid;
  int bm = swz / nt, bn = swz % nt;
  gemm_core<EPI>(A, Bt, Cv, M, N, K, bm, bn, scale, bias, resid, Alds, Blds);
}

// ---------- all 6 KV projections in one launch
__global__ __launch_bounds__(256, 2)
void kv_gemm(const u16* __restrict__ etxt, const u16* __restrict__ eimg, const u16* __restrict__ elbl,
             const u16* __restrict__ wk,   const u16* __restrict__ wv,
             const u16* __restrict__ wkip, const u16* __restrict__ wvip,
             const u16* __restrict__ wklb, const u16* __restrict__ wvlb,
             u16* ktxt, u16* vtxt, u16* kimg, u16* vimg, u16* klbl, u16* vlbl) {
  __shared__ u16 Alds[128 * 64];
  __shared__ u16 Blds[128 * 64];
  int bn = blockIdx.x;       // 0..9
  int my = blockIdx.y;       // 0..4 : 0-2 txt tiles, 3 img, 4 lbl
  int kv = blockIdx.z;       // 0=K 1=V
  const u16 *A, *Bt; u16* C; int M, bm;
  if (my < 3)      { A = etxt; M = 308; bm = my; Bt = kv ? wv   : wk;   C = kv ? vtxt : ktxt; }
  else if (my == 3){ A = eimg; M = 16;  bm = 0;  Bt = kv ? wvip : wkip; C = kv ? vimg : kimg; }
  else             { A = elbl; M = 16;  bm = 0;  Bt = kv ? wvlb : wklb; C = kv ? vlbl : klbl; }
  gemm_core<0>(A, Bt, C, M, 1280, 2048, bm, bn, 1.f, nullptr, nullptr, Alds, Blds);
}

// ---------- fused attention (unchanged from round 0)
#define QSTR 72
#define PSTR 104

__global__ __launch_bounds__(256, 2)
void attn_kern(const u16* __restrict__ q,
               const u16* __restrict__ ktxt, const u16* __restrict__ vtxt,
               const u16* __restrict__ kimg, const u16* __restrict__ vimg,
               const u16* __restrict__ klbl, const u16* __restrict__ vlbl,
               u16* __restrict__ outa) {
  __shared__ __align__(16) char smem[45568];
  u16* Qs = (u16*)smem;
  u16* Ks = (u16*)(smem + 18432);
  u16* Ps = (u16*)smem;
  u16* Vt = (u16*)(smem + 32256);

  int st = blockIdx.x, h = blockIdx.y, b = blockIdx.z;
  int t = threadIdx.x, lane = t & 63, w = t >> 6;
  int s0 = st * 128;
  int c = lane & 15, g = lane >> 4;

  for (int i = t; i < 27136 / 16; i += 256)
    ((uint4*)(smem + 18432))[i] = make_uint4(0, 0, 0, 0);
#pragma unroll
  for (int i = 0; i < 4; i++) {
    int cid = t + i * 256; int r = cid >> 3, c8 = cid & 7;
    *(uint4*)&Qs[r * QSTR + c8 * 8] =
        *(const uint4*)(q + (size_t)(b * N_S + s0 + r) * N_C + h * N_D + c8 * 8);
  }
  __syncthreads();
  for (int cid = t; cid < 680; cid += 256) {
    int l = cid >> 3, c8 = cid & 7;
    const u16* p;
    if (l < 77)      p = ktxt + (size_t)(b * 77 + l) * N_C + h * N_D + c8 * 8;
    else if (l < 81) p = kimg + (size_t)(b * 4 + l - 77) * N_C + h * N_D + c8 * 8;
    else             p = klbl + (size_t)(b * 4 + l - 81) * N_C + h * N_D + c8 * 8;
    int row = (l < 77) ? l : l + 3;
    *(uint4*)&Ks[row * QSTR + c8 * 8] = *(const uint4*)p;
  }
  for (int e = t; e < 85 * 64; e += 256) {
    int l = e >> 6, d = e & 63;
    const u16* p;
    if (l < 77)      p = vtxt + (size_t)(b * 77 + l) * N_C + h * N_D + d;
    else if (l < 81) p = vimg + (size_t)(b * 4 + l - 77) * N_C + h * N_D + d;
    else             p = vlbl + (size_t)(b * 4 + l - 81) * N_C + h * N_D + d;
    int slot = (l < 77) ? l : l + 3;
    Vt[d * PSTR + slot] = *p;
  }
  __syncthreads();

  f32x4 sacc[2][6] = {};
#pragma unroll
  for (int ks = 0; ks < 2; ks++) {
    bf16x8 aq[2], bk[6];
#pragma unroll
    for (int m = 0; m < 2; m++)
      aq[m] = *(bf16x8*)&Qs[(w * 32 + m * 16 + c) * QSTR + ks * 32 + g * 8];
#pragma unroll
    for (int n = 0; n < 6; n++)
      bk[n] = *(bf16x8*)&Ks[(n * 16 + c) * QSTR + ks * 32 + g * 8];
#pragma unroll
    for (int m = 0; m < 2; m++)
#pragma unroll
      for (int n = 0; n < 6; n++)
        sacc[m][n] = __builtin_amdgcn_mfma_f32_16x16x32_bf16(aq[m], bk[n], sacc[m][n], 0, 0, 0);
  }
  __syncthreads();

  const float NEG = -1e30f;
#pragma unroll
  for (int m = 0; m < 2; m++) {
#pragma unroll
    for (int j = 0; j < 4; j++) {
      float tmax = NEG;
#pragma unroll
      for (int n = 0; n < 5; n++)
        if (n * 16 + c < 77) tmax = fmaxf(tmax, sacc[m][n][j]);
#pragma unroll
      for (int off = 1; off < 16; off <<= 1) tmax = fmaxf(tmax, __shfl_xor(tmax, off));
      float pv[5], tsum = 0.f;
#pragma unroll
      for (int n = 0; n < 5; n++) {
        float v = (n * 16 + c < 77) ? __expf(sacc[m][n][j] - tmax) : 0.f;
        pv[n] = v; tsum += v;
      }
#pragma unroll
      for (int off = 1; off < 16; off <<= 1) tsum += __shfl_xor(tsum, off);
      float v5 = sacc[m][5][j];
      float imax = (c < 4) ? v5 : NEG;
#pragma unroll
      for (int off = 1; off < 16; off <<= 1) imax = fmaxf(imax, __shfl_xor(imax, off));
      float ie = (c < 4) ? __expf(v5 - imax) : 0.f, isum = ie;
#pragma unroll
      for (int off = 1; off < 16; off <<= 1) isum += __shfl_xor(isum, off);
      float lmax = (c >= 4 && c < 8) ? v5 : NEG;
#pragma unroll
      for (int off = 1; off < 16; off <<= 1) lmax = fmaxf(lmax, __shfl_xor(lmax, off));
      float le = (c >= 4 && c < 8) ? __expf(v5 - lmax) : 0.f, lsum = le;
#pragma unroll
      for (int off = 1; off < 16; off <<= 1) lsum += __shfl_xor(lsum, off);

      float rt = 1.f / tsum;
      float p5 = (c < 4) ? ie / isum : ((c < 8) ? le / lsum : 0.f);
      int rowl = w * 32 + m * 16 + g * 4 + j;
#pragma unroll
      for (int n = 0; n < 5; n++)
        Ps[rowl * PSTR + n * 16 + c] = f2b(pv[n] * rt);
      Ps[rowl * PSTR + 80 + c] = f2b(p5);
    }
  }
  __syncthreads();

  f32x4 oacc[2][4] = {};
#pragma unroll
  for (int ks = 0; ks < 3; ks++) {
    bf16x8 ap[2], bv[4];
#pragma unroll
    for (int m = 0; m < 2; m++)
      ap[m] = *(bf16x8*)&Ps[(w * 32 + m * 16 + c) * PSTR + ks * 32 + g * 8];
#pragma unroll
    for (int n = 0; n < 4; n++)
      bv[n] = *(bf16x8*)&Vt[(n * 16 + c) * PSTR + ks * 32 + g * 8];
#pragma unroll
    for (int m = 0; m < 2; m++)
#pragma unroll
      for (int n = 0; n < 4; n++)
        oacc[m][n] = __builtin_amdgcn_mfma_f32_16x16x32_bf16(ap[m], bv[n], oacc[m][n], 0, 0, 0);
  }

#pragma unroll
  for (int m = 0; m < 2; m++) {
    int rbase = w * 32 + m * 16 + g * 4;
#pragma unroll
    for (int n = 0; n < 4; n++) {
      int d = n * 16 + c;
#pragma unroll
      for (int j = 0; j < 4; j++) {
        int s = s0 + rbase + j;
        outa[(size_t)(b * N_S + s) * N_C + h * N_D + d] = f2b(oacc[m][n][j]);
      }
    }
  }
}

extern "C" void kernel_launch(void* const* d_in, const int* in_sizes, int n_in,
                              void* d_out, int out_size, void* d_ws, size_t ws_size,
                              hipStream_t stream) {
  const float* hs   = (const float*)d_in[0];
  const float* enc  = (const float*)d_in[1];
  const float* Wq   = (const float*)d_in[2];
  const float* Wk   = (const float*)d_in[3];
  const float* Wv   = (const float*)d_in[4];
  const float* Wkip = (const float*)d_in[5];
  const float* Wvip = (const float*)d_in[6];
  const float* Wklb = (const float*)d_in[7];
  const float* Wvlb = (const float*)d_in[8];
  const float* Wo   = (const float*)d_in[9];
  const float* bo   = (const float*)d_in[10];

  if (ws_size < 83087360u) return;
  char* ws = (char*)d_ws;
  u16* wq_t   = (u16*)(ws + 0);
  u16* wo_t   = (u16*)(ws + 3276800);
  u16* wk_t   = (u16*)(ws + 6553600);
  u16* wv_t   = (u16*)(ws + 11796480);
  u16* wkip_t = (u16*)(ws + 17039360);
  u16* wvip_t = (u16*)(ws + 22282240);
  u16* wklb_t = (u16*)(ws + 27525120);
  u16* wvlb_t = (u16*)(ws + 32768000);
  u16* etxt   = (u16*)(ws + 38010880);
  u16* eimg   = (u16*)(ws + 39272448);
  u16* elbl   = (u16*)(ws + 39337984);
  u16* ktxt   = (u16*)(ws + 39403520);
  u16* vtxt   = (u16*)(ws + 40192000);
  u16* kimg   = (u16*)(ws + 40980480);
  u16* vimg   = (u16*)(ws + 41021440);
  u16* klbl   = (u16*)(ws + 41062400);
  u16* vlbl   = (u16*)(ws + 41103360);
  u16* attn   = (u16*)(ws + 41144320);
  // d_out (84 MB): lower half = q bf16, upper half = hs bf16; both consumed
  // before the final O-proj overwrites d_out with f32 output.
  u16* qbuf   = (u16*)d_out;
  u16* hsb    = (u16*)d_out + (size_t)N_S * N_B * N_C;

  // hs -> bf16
  k_cvt<<<2048, 256, 0, stream>>>(hs, hsb, (N_B * N_S * N_C) / 8);

  // all 8 weight transposes in one launch
  TPargs tp;
  tp.s[0] = Wq;   tp.d[0] = wq_t;   tp.K[0] = 1280;
  tp.s[1] = Wo;   tp.d[1] = wo_t;   tp.K[1] = 1280;
  tp.s[2] = Wk;   tp.d[2] = wk_t;   tp.K[2] = 2048;
  tp.s[3] = Wv;   tp.d[3] = wv_t;   tp.K[3] = 2048;
  tp.s[4] = Wkip; tp.d[4] = wkip_t; tp.K[4] = 2048;
  tp.s[5] = Wvip; tp.d[5] = wvip_t; tp.K[5] = 2048;
  tp.s[6] = Wklb; tp.d[6] = wklb_t; tp.K[6] = 2048;
  tp.s[7] = Wvlb; tp.d[7] = wvlb_t; tp.K[7] = 2048;
  k_transpose8<<<dim3(40, 64, 8), dim3(32, 8), 0, stream>>>(tp);

  k_encpack<<<340, 256, 0, stream>>>(enc, etxt, eimg, elbl);

  // Q = hs @ Wq scaled by D^-0.5
  gemm97<1><<<1280, 256, 0, stream>>>(hsb, wq_t, qbuf, 16384, 1280, 1280,
                                      0.125f, nullptr, nullptr);
  // all 6 KV projections, one launch
  kv_gemm<<<dim3(10, 5, 2), 256, 0, stream>>>(etxt, eimg, elbl,
                                              wk_t, wv_t, wkip_t, wvip_t, wklb_t, wvlb_t,
                                              ktxt, vtxt, kimg, vimg, klbl, vlbl);

  attn_kern<<<dim3(32, N_H, N_B), 256, 0, stream>>>(qbuf, ktxt, vtxt, kimg, vimg,
                                                    klbl, vlbl, attn);
  // out = attn @ Wo + bo + hs
  gemm97<2><<<1280, 256, 0, stream>>>(attn, wo_t, d_out, 16384, 1280, 1280,
                                      1.f, bo, hs);
}

// Round 3
// 321.484 us; speedup vs baseline: 1.9103x; 1.0630x over previous
//
#include <hip/hip_runtime.h>
#include <hip/hip_bf16.h>

typedef unsigned short u16;
using f32x4  = __attribute__((ext_vector_type(4))) float;
using bf16x8 = __attribute__((ext_vector_type(8))) short;

#define N_B 4
#define N_S 4096
#define N_C 1280
#define N_DC 2048
#define N_H 20
#define N_D 64

__device__ __forceinline__ u16 f2b(float f) {
  union { float f; unsigned u; } x; x.f = f;
  return (u16)((x.u + 0x7fffu + ((x.u >> 16) & 1u)) >> 16);
}

__device__ __forceinline__ void gld16(const u16* g, u16* l) {
  __builtin_amdgcn_global_load_lds(
      (const __attribute__((address_space(1))) unsigned int*)(g),
      (__attribute__((address_space(3))) unsigned int*)(l), 16, 0, 0);
}

// ---------- hs f32 -> bf16
__global__ void k_cvt(const float* __restrict__ src, u16* __restrict__ dst, int n8) {
  for (int i = blockIdx.x * 256 + threadIdx.x; i < n8; i += gridDim.x * 256) {
    const float4 v0 = *(const float4*)(src + (size_t)i * 8);
    const float4 v1 = *(const float4*)(src + (size_t)i * 8 + 4);
    alignas(16) u16 t[8];
    t[0] = f2b(v0.x); t[1] = f2b(v0.y); t[2] = f2b(v0.z); t[3] = f2b(v0.w);
    t[4] = f2b(v1.x); t[5] = f2b(v1.y); t[6] = f2b(v1.z); t[7] = f2b(v1.w);
    *(uint4*)(dst + (size_t)i * 8) = *(uint4*)t;
  }
}

// ---------- batched weight transpose + bf16
struct TPargs { const float* s[8]; u16* d[8]; int K[8]; };

__global__ void k_transpose8(TPargs a) {
  int z = blockIdx.z;
  const float* __restrict__ src = a.s[z];
  u16* __restrict__ dst = a.d[z];
  int K = a.K[z];
  int k0 = blockIdx.y * 32;
  if (k0 >= K) return;
  __shared__ float tl[32][33];
  int n0 = blockIdx.x * 32;
  int tx = threadIdx.x, ty = threadIdx.y;
#pragma unroll
  for (int j = 0; j < 32; j += 8)
    tl[ty + j][tx] = src[(size_t)(k0 + ty + j) * N_C + (n0 + tx)];
  __syncthreads();
#pragma unroll
  for (int j = 0; j < 32; j += 8)
    dst[(size_t)(n0 + ty + j) * K + (k0 + tx)] = f2b(tl[tx][ty + j]);
}

// ---------- pack encoder rows
__global__ void k_encpack(const float* __restrict__ enc, u16* __restrict__ txt,
                          u16* __restrict__ img, u16* __restrict__ lbl) {
  int row = blockIdx.x;
  int b = row / 85, l = row % 85;
  const float* s = enc + (size_t)row * N_DC;
  u16* d;
  if (l < 77)      d = txt + (size_t)(b * 77 + l) * N_DC;
  else if (l < 81) d = img + (size_t)(b * 4 + (l - 77)) * N_DC;
  else             d = lbl + (size_t)(b * 4 + (l - 81)) * N_DC;
  for (int i = threadIdx.x; i < N_DC; i += 256) d[i] = f2b(s[i]);
}

// ================= 256x256 8-phase GEMM (T2+T3+T4+T5) =================
// C[M x N] = A[M x K](bf16) * Bt[N x K]^T.  512 thr = 8 waves (2M x 4N),
// wave tile 128x64, BK=64, LDS 128KB double-buffered, XOR slot swizzle.
// EPI: 1 = bf16 store * scale, 2 = f32 store + bias + resid

__device__ __forceinline__ void stage_half8(const u16* __restrict__ gbase, int ldK,
                                            int row0, int kk, u16* ldsbase,
                                            int w, int lane) {
  const int gslot = (((lane & 7) ^ (lane >> 3)) << 3);
#pragma unroll
  for (int j = 0; j < 2; j++) {
    int r = j * 64 + w * 8 + (lane >> 3);
    gld16(gbase + (size_t)(row0 + r) * ldK + kk + gslot,
          ldsbase + (j * 512 + w * 64) * 8);
  }
}

#define RD_A(dst, aoff, mh)                                                  \
  _Pragma("unroll") for (int m = 0; m < 4; m++) {                            \
    _Pragma("unroll") for (int ks = 0; ks < 2; ks++) {                       \
      int row = wr * 128 + (mh) * 64 + m * 16 + lrow;                        \
      int slot = (ks * 4 + g) ^ (lane & 7);                                  \
      dst[m][ks] = *(const bf16x8*)&lds[(aoff) + row * 64 + slot * 8];       \
    }                                                                        \
  }

#define RD_B(dst, boff, nh)                                                  \
  _Pragma("unroll") for (int n = 0; n < 2; n++) {                            \
    _Pragma("unroll") for (int ks = 0; ks < 2; ks++) {                       \
      int row = wc * 64 + (nh) * 32 + n * 16 + lrow;                         \
      int slot = (ks * 4 + g) ^ (lane & 7);                                  \
      dst[n][ks] = *(const bf16x8*)&lds[(boff) + row * 64 + slot * 8];       \
    }                                                                        \
  }

#define MFMA_Q(af, bf, mh, nh)                                               \
  _Pragma("unroll") for (int m = 0; m < 4; m++) {                            \
    _Pragma("unroll") for (int n = 0; n < 2; n++) {                          \
      _Pragma("unroll") for (int ks = 0; ks < 2; ks++)                       \
        acc[(mh) * 4 + m][(nh) * 2 + n] = __builtin_amdgcn_mfma_f32_16x16x32_bf16( \
            af[m][ks], bf[n][ks], acc[(mh) * 4 + m][(nh) * 2 + n], 0, 0, 0); \
    }                                                                        \
  }

#define BARR()  __builtin_amdgcn_s_barrier()
#define LGKM0() asm volatile("s_waitcnt lgkmcnt(0)" ::: "memory")
#define VM4()   asm volatile("s_waitcnt vmcnt(4)" ::: "memory")
#define PRIO(x) __builtin_amdgcn_s_setprio(x)

template<int EPI>
__global__ __launch_bounds__(512, 1)
void gemm8p(const u16* __restrict__ A, const u16* __restrict__ Bt,
            void* __restrict__ Cv, int M, int N, int K, float scale,
            const float* __restrict__ bias, const float* __restrict__ resid) {
  // u16 regions: bufA0 [0,16384) bufB0 [16384,32768) bufA1 [32768,49152) bufB1 [49152,65536)
  __shared__ __align__(16) u16 lds[65536];
  const int t = threadIdx.x, lane = t & 63, w = t >> 6;
  const int wr = w >> 2, wc = w & 3;
  const int lrow = lane & 15, g = lane >> 4;

  int nt = N >> 8;
  int nwg = gridDim.x, bid = blockIdx.x;
  int swz = ((nwg & 7) == 0) ? ((bid & 7) * (nwg >> 3) + (bid >> 3)) : bid;
  int bm = swz / nt, bn = swz % nt;

  const u16* Ag = A  + (size_t)bm * 256 * K;
  const u16* Bg = Bt + (size_t)bn * 256 * K;
  const int NT = K >> 6;

  f32x4 acc[8][4] = {};
  bf16x8 a0[4][2], a1[4][2], b0[2][2], b1[2][2];

  // prologue: tile0 -> buf0 (all 4 halves), tile1 -> buf1 (A halves)
  stage_half8(Ag, K, 0,   0,  lds + 0,     w, lane);
  stage_half8(Ag, K, 128, 0,  lds + 8192,  w, lane);
  stage_half8(Bg, K, 0,   0,  lds + 16384, w, lane);
  stage_half8(Bg, K, 128, 0,  lds + 24576, w, lane);
  stage_half8(Ag, K, 0,   64, lds + 32768, w, lane);
  stage_half8(Ag, K, 128, 64, lds + 40960, w, lane);
  VM4();
  BARR();

  for (int i = 0; i < (NT >> 1); i++) {
    int kt = 2 * i;
    int k1 = (kt + 1) << 6;
    int k2 = (kt + 2 < NT) ? ((kt + 2) << 6) : 0;
    int k3 = (kt + 3 < NT) ? ((kt + 3) << 6) : 0;
    // ---- p1: tile t (buf0)
    RD_A(a0, 0, 0); RD_B(b0, 16384, 0);
    stage_half8(Bg, K, 0, k1, lds + 49152, w, lane);
    BARR(); LGKM0(); PRIO(1); MFMA_Q(a0, b0, 0, 0); PRIO(0); BARR();
    // ---- p2
    RD_A(a1, 0, 1);
    stage_half8(Bg, K, 128, k1, lds + 57344, w, lane);
    BARR(); LGKM0(); PRIO(1); MFMA_Q(a1, b0, 1, 0); PRIO(0); BARR();
    // ---- p3
    RD_B(b1, 16384, 1);
    stage_half8(Ag, K, 0, k2, lds + 0, w, lane);
    BARR(); LGKM0(); PRIO(1); MFMA_Q(a0, b1, 0, 1); PRIO(0); BARR();
    // ---- p4
    stage_half8(Ag, K, 128, k2, lds + 8192, w, lane);
    BARR(); PRIO(1); MFMA_Q(a1, b1, 1, 1); PRIO(0); VM4(); BARR();
    // ---- p5: tile t+1 (buf1)
    RD_A(a0, 32768, 0); RD_B(b0, 49152, 0);
    stage_half8(Bg, K, 0, k2, lds + 16384, w, lane);
    BARR(); LGKM0(); PRIO(1); MFMA_Q(a0, b0, 0, 0); PRIO(0); BARR();
    // ---- p6
    RD_A(a1, 32768, 1);
    stage_half8(Bg, K, 128, k2, lds + 24576, w, lane);
    BARR(); LGKM0(); PRIO(1); MFMA_Q(a1, b0, 1, 0); PRIO(0); BARR();
    // ---- p7
    RD_B(b1, 49152, 1);
    stage_half8(Ag, K, 0, k3, lds + 32768, w, lane);
    BARR(); LGKM0(); PRIO(1); MFMA_Q(a0, b1, 0, 1); PRIO(0); BARR();
    // ---- p8
    stage_half8(Ag, K, 128, k3, lds + 40960, w, lane);
    BARR(); PRIO(1); MFMA_Q(a1, b1, 1, 1); PRIO(0); VM4(); BARR();
  }

  // epilogue
#pragma unroll
  for (int m = 0; m < 8; m++) {
    int row = bm * 256 + wr * 128 + m * 16 + g * 4;
#pragma unroll
    for (int n = 0; n < 4; n++) {
      int col = bn * 256 + wc * 64 + n * 16 + lrow;
#pragma unroll
      for (int j = 0; j < 4; j++) {
        float v = acc[m][n][j];
        if constexpr (EPI == 1)
          ((u16*)Cv)[(size_t)(row + j) * N + col] = f2b(v * scale);
        else
          ((float*)Cv)[(size_t)(row + j) * N + col] =
              v + bias[col] + resid[(size_t)(row + j) * N + col];
      }
    }
  }
}

// ---------- 2-phase GEMM core (kept for the small KV projections)
template<int EPI>
__device__ __forceinline__ void gemm_core(
    const u16* __restrict__ A, const u16* __restrict__ Bt, void* __restrict__ Cv,
    int M, int N, int K, int bm, int bn, float scale,
    const float* __restrict__ bias, const float* __restrict__ resid,
    u16* Alds, u16* Blds) {
  int t = threadIdx.x, lane = t & 63, w = t >> 6;
  int wm = w >> 1, wn = w & 1;
  f32x4 acc[4][4] = {};
  int c8 = lane & 7;
  int rsub = lane >> 3;

  for (int k0 = 0; k0 < K; k0 += 64) {
    if (k0) __syncthreads();
#pragma unroll
    for (int i = 0; i < 4; i++) {
      int rloc = w * 32 + i * 8;
      int ra = bm * 128 + rloc + rsub; if (ra >= M) ra = M - 1;
      int rb = bn * 128 + rloc + rsub;
      gld16(A  + (size_t)ra * K + k0 + c8 * 8, &Alds[rloc * 64]);
      gld16(Bt + (size_t)rb * K + k0 + c8 * 8, &Blds[rloc * 64]);
    }
    __syncthreads();
#pragma unroll
    for (int ks = 0; ks < 2; ks++) {
      bf16x8 afr[4], bfr[4];
#pragma unroll
      for (int m = 0; m < 4; m++)
        afr[m] = *(bf16x8*)&Alds[(wm * 64 + m * 16 + (lane & 15)) * 64 + ks * 32 + (lane >> 4) * 8];
#pragma unroll
      for (int n = 0; n < 4; n++)
        bfr[n] = *(bf16x8*)&Blds[(wn * 64 + n * 16 + (lane & 15)) * 64 + ks * 32 + (lane >> 4) * 8];
#pragma unroll
      for (int m = 0; m < 4; m++)
#pragma unroll
        for (int n = 0; n < 4; n++)
          acc[m][n] = __builtin_amdgcn_mfma_f32_16x16x32_bf16(afr[m], bfr[n], acc[m][n], 0, 0, 0);
    }
  }

#pragma unroll
  for (int m = 0; m < 4; m++) {
    int row = bm * 128 + wm * 64 + m * 16 + ((lane >> 4) << 2);
#pragma unroll
    for (int n = 0; n < 4; n++) {
      int col = bn * 128 + wn * 64 + n * 16 + (lane & 15);
#pragma unroll
      for (int j = 0; j < 4; j++) {
        int r = row + j;
        if (r >= M) continue;
        float v = acc[m][n][j];
        ((u16*)Cv)[(size_t)r * N + col] = f2b(v);
      }
    }
  }
}

__global__ __launch_bounds__(256, 2)
void kv_gemm(const u16* __restrict__ etxt, const u16* __restrict__ eimg, const u16* __restrict__ elbl,
             const u16* __restrict__ wk,   const u16* __restrict__ wv,
             const u16* __restrict__ wkip, const u16* __restrict__ wvip,
             const u16* __restrict__ wklb, const u16* __restrict__ wvlb,
             u16* ktxt, u16* vtxt, u16* kimg, u16* vimg, u16* klbl, u16* vlbl) {
  __shared__ u16 Alds[128 * 64];
  __shared__ u16 Blds[128 * 64];
  int bn = blockIdx.x;
  int my = blockIdx.y;
  int kv = blockIdx.z;
  const u16 *A, *Bt; u16* C; int M, bm;
  if (my < 3)      { A = etxt; M = 308; bm = my; Bt = kv ? wv   : wk;   C = kv ? vtxt : ktxt; }
  else if (my == 3){ A = eimg; M = 16;  bm = 0;  Bt = kv ? wvip : wkip; C = kv ? vimg : kimg; }
  else             { A = elbl; M = 16;  bm = 0;  Bt = kv ? wvlb : wklb; C = kv ? vlbl : klbl; }
  gemm_core<0>(A, Bt, C, M, 1280, 2048, bm, bn, 1.f, nullptr, nullptr, Alds, Blds);
}

// ---------- fused attention (unchanged)
#define QSTR 72
#define PSTR 104

__global__ __launch_bounds__(256, 2)
void attn_kern(const u16* __restrict__ q,
               const u16* __restrict__ ktxt, const u16* __restrict__ vtxt,
               const u16* __restrict__ kimg, const u16* __restrict__ vimg,
               const u16* __restrict__ klbl, const u16* __restrict__ vlbl,
               u16* __restrict__ outa) {
  __shared__ __align__(16) char smem[45568];
  u16* Qs = (u16*)smem;
  u16* Ks = (u16*)(smem + 18432);
  u16* Ps = (u16*)smem;
  u16* Vt = (u16*)(smem + 32256);

  int st = blockIdx.x, h = blockIdx.y, b = blockIdx.z;
  int t = threadIdx.x, lane = t & 63, w = t >> 6;
  int s0 = st * 128;
  int c = lane & 15, g = lane >> 4;

  for (int i = t; i < 27136 / 16; i += 256)
    ((uint4*)(smem + 18432))[i] = make_uint4(0, 0, 0, 0);
#pragma unroll
  for (int i = 0; i < 4; i++) {
    int cid = t + i * 256; int r = cid >> 3, c8 = cid & 7;
    *(uint4*)&Qs[r * QSTR + c8 * 8] =
        *(const uint4*)(q + (size_t)(b * N_S + s0 + r) * N_C + h * N_D + c8 * 8);
  }
  __syncthreads();
  for (int cid = t; cid < 680; cid += 256) {
    int l = cid >> 3, c8 = cid & 7;
    const u16* p;
    if (l < 77)      p = ktxt + (size_t)(b * 77 + l) * N_C + h * N_D + c8 * 8;
    else if (l < 81) p = kimg + (size_t)(b * 4 + l - 77) * N_C + h * N_D + c8 * 8;
    else             p = klbl + (size_t)(b * 4 + l - 81) * N_C + h * N_D + c8 * 8;
    int row = (l < 77) ? l : l + 3;
    *(uint4*)&Ks[row * QSTR + c8 * 8] = *(const uint4*)p;
  }
  for (int e = t; e < 85 * 64; e += 256) {
    int l = e >> 6, d = e & 63;
    const u16* p;
    if (l < 77)      p = vtxt + (size_t)(b * 77 + l) * N_C + h * N_D + d;
    else if (l < 81) p = vimg + (size_t)(b * 4 + l - 77) * N_C + h * N_D + d;
    else             p = vlbl + (size_t)(b * 4 + l - 81) * N_C + h * N_D + d;
    int slot = (l < 77) ? l : l + 3;
    Vt[d * PSTR + slot] = *p;
  }
  __syncthreads();

  f32x4 sacc[2][6] = {};
#pragma unroll
  for (int ks = 0; ks < 2; ks++) {
    bf16x8 aq[2], bk[6];
#pragma unroll
    for (int m = 0; m < 2; m++)
      aq[m] = *(bf16x8*)&Qs[(w * 32 + m * 16 + c) * QSTR + ks * 32 + g * 8];
#pragma unroll
    for (int n = 0; n < 6; n++)
      bk[n] = *(bf16x8*)&Ks[(n * 16 + c) * QSTR + ks * 32 + g * 8];
#pragma unroll
    for (int m = 0; m < 2; m++)
#pragma unroll
      for (int n = 0; n < 6; n++)
        sacc[m][n] = __builtin_amdgcn_mfma_f32_16x16x32_bf16(aq[m], bk[n], sacc[m][n], 0, 0, 0);
  }
  __syncthreads();

  const float NEG = -1e30f;
#pragma unroll
  for (int m = 0; m < 2; m++) {
#pragma unroll
    for (int j = 0; j < 4; j++) {
      float tmax = NEG;
#pragma unroll
      for (int n = 0; n < 5; n++)
        if (n * 16 + c < 77) tmax = fmaxf(tmax, sacc[m][n][j]);
#pragma unroll
      for (int off = 1; off < 16; off <<= 1) tmax = fmaxf(tmax, __shfl_xor(tmax, off));
      float pv[5], tsum = 0.f;
#pragma unroll
      for (int n = 0; n < 5; n++) {
        float v = (n * 16 + c < 77) ? __expf(sacc[m][n][j] - tmax) : 0.f;
        pv[n] = v; tsum += v;
      }
#pragma unroll
      for (int off = 1; off < 16; off <<= 1) tsum += __shfl_xor(tsum, off);
      float v5 = sacc[m][5][j];
      float imax = (c < 4) ? v5 : NEG;
#pragma unroll
      for (int off = 1; off < 16; off <<= 1) imax = fmaxf(imax, __shfl_xor(imax, off));
      float ie = (c < 4) ? __expf(v5 - imax) : 0.f, isum = ie;
#pragma unroll
      for (int off = 1; off < 16; off <<= 1) isum += __shfl_xor(isum, off);
      float lmax = (c >= 4 && c < 8) ? v5 : NEG;
#pragma unroll
      for (int off = 1; off < 16; off <<= 1) lmax = fmaxf(lmax, __shfl_xor(lmax, off));
      float le = (c >= 4 && c < 8) ? __expf(v5 - lmax) : 0.f, lsum = le;
#pragma unroll
      for (int off = 1; off < 16; off <<= 1) lsum += __shfl_xor(lsum, off);

      float rt = 1.f / tsum;
      float p5 = (c < 4) ? ie / isum : ((c < 8) ? le / lsum : 0.f);
      int rowl = w * 32 + m * 16 + g * 4 + j;
#pragma unroll
      for (int n = 0; n < 5; n++)
        Ps[rowl * PSTR + n * 16 + c] = f2b(pv[n] * rt);
      Ps[rowl * PSTR + 80 + c] = f2b(p5);
    }
  }
  __syncthreads();

  f32x4 oacc[2][4] = {};
#pragma unroll
  for (int ks = 0; ks < 3; ks++) {
    bf16x8 ap[2], bv[4];
#pragma unroll
    for (int m = 0; m < 2; m++)
      ap[m] = *(bf16x8*)&Ps[(w * 32 + m * 16 + c) * PSTR + ks * 32 + g * 8];
#pragma unroll
    for (int n = 0; n < 4; n++)
      bv[n] = *(bf16x8*)&Vt[(n * 16 + c) * PSTR + ks * 32 + g * 8];
#pragma unroll
    for (int m = 0; m < 2; m++)
#pragma unroll
      for (int n = 0; n < 4; n++)
        oacc[m][n] = __builtin_amdgcn_mfma_f32_16x16x32_bf16(ap[m], bv[n], oacc[m][n], 0, 0, 0);
  }

#pragma unroll
  for (int m = 0; m < 2; m++) {
    int rbase = w * 32 + m * 16 + g * 4;
#pragma unroll
    for (int n = 0; n < 4; n++) {
      int d = n * 16 + c;
#pragma unroll
      for (int j = 0; j < 4; j++) {
        int s = s0 + rbase + j;
        outa[(size_t)(b * N_S + s) * N_C + h * N_D + d] = f2b(oacc[m][n][j]);
      }
    }
  }
}

extern "C" void kernel_launch(void* const* d_in, const int* in_sizes, int n_in,
                              void* d_out, int out_size, void* d_ws, size_t ws_size,
                              hipStream_t stream) {
  const float* hs   = (const float*)d_in[0];
  const float* enc  = (const float*)d_in[1];
  const float* Wq   = (const float*)d_in[2];
  const float* Wk   = (const float*)d_in[3];
  const float* Wv   = (const float*)d_in[4];
  const float* Wkip = (const float*)d_in[5];
  const float* Wvip = (const float*)d_in[6];
  const float* Wklb = (const float*)d_in[7];
  const float* Wvlb = (const float*)d_in[8];
  const float* Wo   = (const float*)d_in[9];
  const float* bo   = (const float*)d_in[10];

  if (ws_size < 83087360u) return;
  char* ws = (char*)d_ws;
  u16* wq_t   = (u16*)(ws + 0);
  u16* wo_t   = (u16*)(ws + 3276800);
  u16* wk_t   = (u16*)(ws + 6553600);
  u16* wv_t   = (u16*)(ws + 11796480);
  u16* wkip_t = (u16*)(ws + 17039360);
  u16* wvip_t = (u16*)(ws + 22282240);
  u16* wklb_t = (u16*)(ws + 27525120);
  u16* wvlb_t = (u16*)(ws + 32768000);
  u16* etxt   = (u16*)(ws + 38010880);
  u16* eimg   = (u16*)(ws + 39272448);
  u16* elbl   = (u16*)(ws + 39337984);
  u16* ktxt   = (u16*)(ws + 39403520);
  u16* vtxt   = (u16*)(ws + 40192000);
  u16* kimg   = (u16*)(ws + 40980480);
  u16* vimg   = (u16*)(ws + 41021440);
  u16* klbl   = (u16*)(ws + 41062400);
  u16* vlbl   = (u16*)(ws + 41103360);
  u16* attn   = (u16*)(ws + 41144320);
  // d_out (84 MB): lower half = q bf16, upper half = hs bf16; both consumed
  // before the final O-proj overwrites d_out with f32 output.
  u16* qbuf   = (u16*)d_out;
  u16* hsb    = (u16*)d_out + (size_t)N_S * N_B * N_C;

  k_cvt<<<2048, 256, 0, stream>>>(hs, hsb, (N_B * N_S * N_C) / 8);

  TPargs tp;
  tp.s[0] = Wq;   tp.d[0] = wq_t;   tp.K[0] = 1280;
  tp.s[1] = Wo;   tp.d[1] = wo_t;   tp.K[1] = 1280;
  tp.s[2] = Wk;   tp.d[2] = wk_t;   tp.K[2] = 2048;
  tp.s[3] = Wv;   tp.d[3] = wv_t;   tp.K[3] = 2048;
  tp.s[4] = Wkip; tp.d[4] = wkip_t; tp.K[4] = 2048;
  tp.s[5] = Wvip; tp.d[5] = wvip_t; tp.K[5] = 2048;
  tp.s[6] = Wklb; tp.d[6] = wklb_t; tp.K[6] = 2048;
  tp.s[7] = Wvlb; tp.d[7] = wvlb_t; tp.K[7] = 2048;
  k_transpose8<<<dim3(40, 64, 8), dim3(32, 8), 0, stream>>>(tp);

  k_encpack<<<340, 256, 0, stream>>>(enc, etxt, eimg, elbl);

  // Q = hs @ Wq scaled by D^-0.5 (8-phase 256^2)
  gemm8p<1><<<320, 512, 0, stream>>>(hsb, wq_t, qbuf, 16384, 1280, 1280,
                                     0.125f, nullptr, nullptr);
  // all 6 KV projections, one launch (2-phase)
  kv_gemm<<<dim3(10, 5, 2), 256, 0, stream>>>(etxt, eimg, elbl,
                                              wk_t, wv_t, wkip_t, wvip_t, wklb_t, wvlb_t,
                                              ktxt, vtxt, kimg, vimg, klbl, vlbl);

  attn_kern<<<dim3(32, N_H, N_B), 256, 0, stream>>>(qbuf, ktxt, vtxt, kimg, vimg,
                                                    klbl, vlbl, attn);
  // out = attn @ Wo + bo + hs (8-phase 256^2)
  gemm8p<2><<<320, 512, 0, stream>>>(attn, wo_t, d_out, 16384, 1280, 1280,
                                     1.f, bo, hs);
}

// Round 5
// 266.472 us; speedup vs baseline: 2.3047x; 1.2064x over previous
//
#include <hip/hip_runtime.h>
#include <hip/hip_bf16.h>

typedef unsigned short u16;
using f32x4  = __attribute__((ext_vector_type(4))) float;
using bf16x8 = __attribute__((ext_vector_type(8))) short;

#define N_B 4
#define N_S 4096
#define N_C 1280
#define N_DC 2048
#define N_H 20
#define N_D 64

__device__ __forceinline__ u16 f2b(float f) {
  union { float f; unsigned u; } x; x.f = f;
  return (u16)((x.u + 0x7fffu + ((x.u >> 16) & 1u)) >> 16);
}

__device__ __forceinline__ void gld16(const u16* g, u16* l) {
  __builtin_amdgcn_global_load_lds(
      (const __attribute__((address_space(1))) unsigned int*)(g),
      (__attribute__((address_space(3))) unsigned int*)(l), 16, 0, 0);
}

// ---------- hs f32 -> bf16
__global__ void k_cvt(const float* __restrict__ src, u16* __restrict__ dst, int n8) {
  for (int i = blockIdx.x * 256 + threadIdx.x; i < n8; i += gridDim.x * 256) {
    const float4 v0 = *(const float4*)(src + (size_t)i * 8);
    const float4 v1 = *(const float4*)(src + (size_t)i * 8 + 4);
    alignas(16) u16 t[8];
    t[0] = f2b(v0.x); t[1] = f2b(v0.y); t[2] = f2b(v0.z); t[3] = f2b(v0.w);
    t[4] = f2b(v1.x); t[5] = f2b(v1.y); t[6] = f2b(v1.z); t[7] = f2b(v1.w);
    *(uint4*)(dst + (size_t)i * 8) = *(uint4*)t;
  }
}

// ---------- batched weight transpose + bf16
struct TPargs { const float* s[8]; u16* d[8]; int K[8]; };

__global__ void k_transpose8(TPargs a) {
  int z = blockIdx.z;
  const float* __restrict__ src = a.s[z];
  u16* __restrict__ dst = a.d[z];
  int K = a.K[z];
  int k0 = blockIdx.y * 32;
  if (k0 >= K) return;
  __shared__ float tl[32][33];
  int n0 = blockIdx.x * 32;
  int tx = threadIdx.x, ty = threadIdx.y;
#pragma unroll
  for (int j = 0; j < 32; j += 8)
    tl[ty + j][tx] = src[(size_t)(k0 + ty + j) * N_C + (n0 + tx)];
  __syncthreads();
#pragma unroll
  for (int j = 0; j < 32; j += 8)
    dst[(size_t)(n0 + ty + j) * K + (k0 + tx)] = f2b(tl[tx][ty + j]);
}

// ---------- pack encoder rows
__global__ void k_encpack(const float* __restrict__ enc, u16* __restrict__ txt,
                          u16* __restrict__ img, u16* __restrict__ lbl) {
  int row = blockIdx.x;
  int b = row / 85, l = row % 85;
  const float* s = enc + (size_t)row * N_DC;
  u16* d;
  if (l < 77)      d = txt + (size_t)(b * 77 + l) * N_DC;
  else if (l < 81) d = img + (size_t)(b * 4 + (l - 77)) * N_DC;
  else             d = lbl + (size_t)(b * 4 + (l - 81)) * N_DC;
  for (int i = threadIdx.x; i < N_DC; i += 256) d[i] = f2b(s[i]);
}

// ================= 256x320 4-phase GEMM, double-buffered =================
// C[M x N] = A[M x K](bf16) * Bt[N x K]^T.  512 thr = 8 waves (2M x 4N),
// wave tile 128x80, BK=64.
// LDS (u16 offsets): A0 [0,16384) A1 [16384,32768) B0 [32768,53248)
// B1 [53248,73728)  -> 144 KB total.
// Grid = (M/256)*(N/320) = 64*4 = 256 blocks = exactly one full round.
// Per K-tile: 4 phases x 20 MFMA; all 9 prefetch loads for tile t+1 issued
// in p1; single vmcnt(0) drain at end of p4 (cover ~= 80 MFMA > HBM latency).
// EPI: 1 = bf16 store * scale, 2 = f32 store + bias + resid

// stage 64 rows x 64 k (8KB): XOR-swizzled global source, linear LDS dest
__device__ __forceinline__ void stage64(const u16* __restrict__ g, int ldK,
                                        int row0, int kk, u16* ldsb,
                                        int w, int lane) {
  int r = w * 8 + (lane >> 3);
  int gslot = ((lane & 7) ^ (lane >> 3)) << 3;
  gld16(g + (size_t)(row0 + r) * ldK + kk + gslot, ldsb + w * 512);
}
__device__ __forceinline__ void stageA4(const u16* Ag, int K, int kk, u16* ldsb,
                                        int w, int lane) {
#pragma unroll
  for (int j = 0; j < 4; j++)
    stage64(Ag, K, j * 64, kk, ldsb + j * 4096, w, lane);
}
__device__ __forceinline__ void stageB5(const u16* Bg, int K, int kk, u16* ldsb,
                                        int w, int lane) {
#pragma unroll
  for (int j = 0; j < 5; j++)
    stage64(Bg, K, j * 64, kk, ldsb + j * 4096, w, lane);
}

#define RD_A2(aoff, mh)                                                      \
  _Pragma("unroll") for (int mi = 0; mi < 2; mi++) {                         \
    _Pragma("unroll") for (int ks = 0; ks < 2; ks++) {                       \
      int row = wr * 128 + ((mh) * 2 + mi) * 16 + lrow;                      \
      int slot = (ks * 4 + g) ^ (lane & 7);                                  \
      af[mi][ks] = *(const bf16x8*)&lds[(aoff) + row * 64 + slot * 8];       \
    }                                                                        \
  }

#define RD_B5(boff)                                                          \
  _Pragma("unroll") for (int n = 0; n < 5; n++) {                            \
    _Pragma("unroll") for (int ks = 0; ks < 2; ks++) {                       \
      int row = wc * 80 + n * 16 + lrow;                                     \
      int slot = (ks * 4 + g) ^ (lane & 7);                                  \
      bf[n][ks] = *(const bf16x8*)&lds[(boff) + row * 64 + slot * 8];        \
    }                                                                        \
  }

#define MFMA20(mh)                                                           \
  _Pragma("unroll") for (int mi = 0; mi < 2; mi++) {                         \
    _Pragma("unroll") for (int n = 0; n < 5; n++) {                          \
      _Pragma("unroll") for (int ks = 0; ks < 2; ks++)                       \
        acc[(mh) * 2 + mi][n] = __builtin_amdgcn_mfma_f32_16x16x32_bf16(     \
            af[mi][ks], bf[n][ks], acc[(mh) * 2 + mi][n], 0, 0, 0);          \
    }                                                                        \
  }

#define BARR()  __builtin_amdgcn_s_barrier()
#define LGKM0() asm volatile("s_waitcnt lgkmcnt(0)" ::: "memory")
#define VM0()   asm volatile("s_waitcnt vmcnt(0)" ::: "memory")
#define PRIO(x) __builtin_amdgcn_s_setprio(x)

template<int EPI>
__global__ __launch_bounds__(512, 1)
void gemm8p(const u16* __restrict__ A, const u16* __restrict__ Bt,
            void* __restrict__ Cv, int M, int N, int K, float scale,
            const float* __restrict__ bias, const float* __restrict__ resid) {
  __shared__ __align__(16) u16 lds[73728];
  const int t = threadIdx.x, lane = t & 63, w = t >> 6;
  const int wr = w >> 2, wc = w & 3;
  const int lrow = lane & 15, g = lane >> 4;

  int nt = N / 320;
  int nwg = gridDim.x, bid = blockIdx.x;
  int swz = ((nwg & 7) == 0) ? ((bid & 7) * (nwg >> 3) + (bid >> 3)) : bid;
  int bm = swz / nt, bn = swz % nt;

  const u16* Ag = A  + (size_t)bm * 256 * K;
  const u16* Bg = Bt + (size_t)bn * 320 * K;
  const int NT = K >> 6;

  f32x4 acc[8][5] = {};
  bf16x8 af[2][2], bf[5][2];

  // prologue: stage tile0 -> buf0
  stageA4(Ag, K, 0, lds + 0,     w, lane);
  stageB5(Bg, K, 0, lds + 32768, w, lane);
  VM0();
  BARR();

  for (int tt = 0; tt < NT; ++tt) {
    int c = tt & 1;
    int aof  = c * 16384,        bof  = 32768 + c * 20480;
    int aof1 = (c ^ 1) * 16384,  bof1 = 32768 + (c ^ 1) * 20480;
    int kn = (tt + 1 < NT) ? (tt + 1) * 64 : 0;   // dummy restage on last tile
    // p1: read all B + A rows 0-31; issue all 9 prefetch loads for tile t+1
    RD_A2(aof, 0); RD_B5(bof);
    stageA4(Ag, K, kn, lds + aof1, w, lane);
    stageB5(Bg, K, kn, lds + bof1, w, lane);
    BARR(); LGKM0(); PRIO(1); MFMA20(0); PRIO(0); BARR();
    // p2
    RD_A2(aof, 1);
    BARR(); LGKM0(); PRIO(1); MFMA20(1); PRIO(0); BARR();
    // p3
    RD_A2(aof, 2);
    BARR(); LGKM0(); PRIO(1); MFMA20(2); PRIO(0); BARR();
    // p4: drain tile t+1's loads before the boundary barrier
    RD_A2(aof, 3);
    BARR(); LGKM0(); PRIO(1); MFMA20(3); PRIO(0); VM0(); BARR();
  }

  // epilogue
#pragma unroll
  for (int m = 0; m < 8; m++) {
    int row = bm * 256 + wr * 128 + m * 16 + g * 4;
#pragma unroll
    for (int n = 0; n < 5; n++) {
      int col = bn * 320 + wc * 80 + n * 16 + lrow;
#pragma unroll
      for (int j = 0; j < 4; j++) {
        float v = acc[m][n][j];
        if constexpr (EPI == 1)
          ((u16*)Cv)[(size_t)(row + j) * N + col] = f2b(v * scale);
        else
          ((float*)Cv)[(size_t)(row + j) * N + col] =
              v + bias[col] + resid[(size_t)(row + j) * N + col];
      }
    }
  }
}

// ---------- all 6 KV projections in one launch, prefetched 2-phase
__global__ __launch_bounds__(256, 2)
void kv_gemm(const u16* __restrict__ etxt, const u16* __restrict__ eimg, const u16* __restrict__ elbl,
             const u16* __restrict__ wk,   const u16* __restrict__ wv,
             const u16* __restrict__ wkip, const u16* __restrict__ wvip,
             const u16* __restrict__ wklb, const u16* __restrict__ wvlb,
             u16* ktxt, u16* vtxt, u16* kimg, u16* vimg, u16* klbl, u16* vlbl) {
  __shared__ __align__(16) u16 lds[2][2][8192];   // [buf][A/B][128*64]
  int bn = blockIdx.x, my = blockIdx.y, kv = blockIdx.z;
  const u16 *A, *Bt; u16* C; int M, bm;
  if (my < 3)       { A = etxt; M = 308; bm = my; Bt = kv ? wv   : wk;   C = kv ? vtxt : ktxt; }
  else if (my == 3) { A = eimg; M = 16;  bm = 0;  Bt = kv ? wvip : wkip; C = kv ? vimg : kimg; }
  else              { A = elbl; M = 16;  bm = 0;  Bt = kv ? wvlb : wklb; C = kv ? vlbl : klbl; }
  const int K = 2048;
  int t = threadIdx.x, lane = t & 63, w = t >> 6;
  int wm = w >> 1, wn = w & 1;
  int c8 = lane & 7, rsub = lane >> 3;

  f32x4 acc[4][4] = {};

#define KVSTAGE(kt, buf)                                                      \
  {                                                                           \
    int k0 = (kt) * 64;                                                       \
    _Pragma("unroll") for (int i2 = 0; i2 < 4; i2++) {                        \
      int rloc = w * 32 + i2 * 8;                                             \
      int ra = bm * 128 + rloc + rsub; if (ra >= M) ra = M - 1;               \
      int rb = bn * 128 + rloc + rsub;                                        \
      gld16(A  + (size_t)ra * K + k0 + c8 * 8, &lds[buf][0][rloc * 64]);      \
      gld16(Bt + (size_t)rb * K + k0 + c8 * 8, &lds[buf][1][rloc * 64]);      \
    }                                                                         \
  }

  KVSTAGE(0, 0);
  asm volatile("s_waitcnt vmcnt(0)" ::: "memory");
  __syncthreads();
  int cur = 0;
  for (int kt = 0; kt < 32; kt++) {
    if (kt < 31) KVSTAGE(kt + 1, cur ^ 1);
#pragma unroll
    for (int ks = 0; ks < 2; ks++) {
      bf16x8 afr[4], bfr[4];
#pragma unroll
      for (int m = 0; m < 4; m++)
        afr[m] = *(bf16x8*)&lds[cur][0][(wm * 64 + m * 16 + (lane & 15)) * 64 + ks * 32 + (lane >> 4) * 8];
#pragma unroll
      for (int n = 0; n < 4; n++)
        bfr[n] = *(bf16x8*)&lds[cur][1][(wn * 64 + n * 16 + (lane & 15)) * 64 + ks * 32 + (lane >> 4) * 8];
#pragma unroll
      for (int m = 0; m < 4; m++)
#pragma unroll
        for (int n = 0; n < 4; n++)
          acc[m][n] = __builtin_amdgcn_mfma_f32_16x16x32_bf16(afr[m], bfr[n], acc[m][n], 0, 0, 0);
    }
    asm volatile("s_waitcnt vmcnt(0)" ::: "memory");
    __syncthreads();
    cur ^= 1;
  }
#undef KVSTAGE

#pragma unroll
  for (int m = 0; m < 4; m++) {
    int row = bm * 128 + wm * 64 + m * 16 + ((lane >> 4) << 2);
#pragma unroll
    for (int n = 0; n < 4; n++) {
      int col = bn * 128 + wn * 64 + n * 16 + (lane & 15);
#pragma unroll
      for (int j = 0; j < 4; j++) {
        int r = row + j;
        if (r >= M) continue;
        ((u16*)C)[(size_t)r * 1280 + col] = f2b(acc[m][n][j]);
      }
    }
  }
}

// ---------- fused attention (unchanged)
#define QSTR 72
#define PSTR 104

__global__ __launch_bounds__(256, 2)
void attn_kern(const u16* __restrict__ q,
               const u16* __restrict__ ktxt, const u16* __restrict__ vtxt,
               const u16* __restrict__ kimg, const u16* __restrict__ vimg,
               const u16* __restrict__ klbl, const u16* __restrict__ vlbl,
               u16* __restrict__ outa) {
  __shared__ __align__(16) char smem[45568];
  u16* Qs = (u16*)smem;
  u16* Ks = (u16*)(smem + 18432);
  u16* Ps = (u16*)smem;
  u16* Vt = (u16*)(smem + 32256);

  int st = blockIdx.x, h = blockIdx.y, b = blockIdx.z;
  int t = threadIdx.x, lane = t & 63, w = t >> 6;
  int s0 = st * 128;
  int c = lane & 15, g = lane >> 4;

  for (int i = t; i < 27136 / 16; i += 256)
    ((uint4*)(smem + 18432))[i] = make_uint4(0, 0, 0, 0);
#pragma unroll
  for (int i = 0; i < 4; i++) {
    int cid = t + i * 256; int r = cid >> 3, c8 = cid & 7;
    *(uint4*)&Qs[r * QSTR + c8 * 8] =
        *(const uint4*)(q + (size_t)(b * N_S + s0 + r) * N_C + h * N_D + c8 * 8);
  }
  __syncthreads();
  for (int cid = t; cid < 680; cid += 256) {
    int l = cid >> 3, c8 = cid & 7;
    const u16* p;
    if (l < 77)      p = ktxt + (size_t)(b * 77 + l) * N_C + h * N_D + c8 * 8;
    else if (l < 81) p = kimg + (size_t)(b * 4 + l - 77) * N_C + h * N_D + c8 * 8;
    else             p = klbl + (size_t)(b * 4 + l - 81) * N_C + h * N_D + c8 * 8;
    int row = (l < 77) ? l : l + 3;
    *(uint4*)&Ks[row * QSTR + c8 * 8] = *(const uint4*)p;
  }
  for (int e = t; e < 85 * 64; e += 256) {
    int l = e >> 6, d = e & 63;
    const u16* p;
    if (l < 77)      p = vtxt + (size_t)(b * 77 + l) * N_C + h * N_D + d;
    else if (l < 81) p = vimg + (size_t)(b * 4 + l - 77) * N_C + h * N_D + d;
    else             p = vlbl + (size_t)(b * 4 + l - 81) * N_C + h * N_D + d;
    int slot = (l < 77) ? l : l + 3;
    Vt[d * PSTR + slot] = *p;
  }
  __syncthreads();

  f32x4 sacc[2][6] = {};
#pragma unroll
  for (int ks = 0; ks < 2; ks++) {
    bf16x8 aq[2], bk[6];
#pragma unroll
    for (int m = 0; m < 2; m++)
      aq[m] = *(bf16x8*)&Qs[(w * 32 + m * 16 + c) * QSTR + ks * 32 + g * 8];
#pragma unroll
    for (int n = 0; n < 6; n++)
      bk[n] = *(bf16x8*)&Ks[(n * 16 + c) * QSTR + ks * 32 + g * 8];
#pragma unroll
    for (int m = 0; m < 2; m++)
#pragma unroll
      for (int n = 0; n < 6; n++)
        sacc[m][n] = __builtin_amdgcn_mfma_f32_16x16x32_bf16(aq[m], bk[n], sacc[m][n], 0, 0, 0);
  }
  __syncthreads();

  const float NEG = -1e30f;
#pragma unroll
  for (int m = 0; m < 2; m++) {
#pragma unroll
    for (int j = 0; j < 4; j++) {
      float tmax = NEG;
#pragma unroll
      for (int n = 0; n < 5; n++)
        if (n * 16 + c < 77) tmax = fmaxf(tmax, sacc[m][n][j]);
#pragma unroll
      for (int off = 1; off < 16; off <<= 1) tmax = fmaxf(tmax, __shfl_xor(tmax, off));
      float pv[5], tsum = 0.f;
#pragma unroll
      for (int n = 0; n < 5; n++) {
        float v = (n * 16 + c < 77) ? __expf(sacc[m][n][j] - tmax) : 0.f;
        pv[n] = v; tsum += v;
      }
#pragma unroll
      for (int off = 1; off < 16; off <<= 1) tsum += __shfl_xor(tsum, off);
      float v5 = sacc[m][5][j];
      float imax = (c < 4) ? v5 : NEG;
#pragma unroll
      for (int off = 1; off < 16; off <<= 1) imax = fmaxf(imax, __shfl_xor(imax, off));
      float ie = (c < 4) ? __expf(v5 - imax) : 0.f, isum = ie;
#pragma unroll
      for (int off = 1; off < 16; off <<= 1) isum += __shfl_xor(isum, off);
      float lmax = (c >= 4 && c < 8) ? v5 : NEG;
#pragma unroll
      for (int off = 1; off < 16; off <<= 1) lmax = fmaxf(lmax, __shfl_xor(lmax, off));
      float le = (c >= 4 && c < 8) ? __expf(v5 - lmax) : 0.f, lsum = le;
#pragma unroll
      for (int off = 1; off < 16; off <<= 1) lsum += __shfl_xor(lsum, off);

      float rt = 1.f / tsum;
      float p5 = (c < 4) ? ie / isum : ((c < 8) ? le / lsum : 0.f);
      int rowl = w * 32 + m * 16 + g * 4 + j;
#pragma unroll
      for (int n = 0; n < 5; n++)
        Ps[rowl * PSTR + n * 16 + c] = f2b(pv[n] * rt);
      Ps[rowl * PSTR + 80 + c] = f2b(p5);
    }
  }
  __syncthreads();

  f32x4 oacc[2][4] = {};
#pragma unroll
  for (int ks = 0; ks < 3; ks++) {
    bf16x8 ap[2], bv[4];
#pragma unroll
    for (int m = 0; m < 2; m++)
      ap[m] = *(bf16x8*)&Ps[(w * 32 + m * 16 + c) * PSTR + ks * 32 + g * 8];
#pragma unroll
    for (int n = 0; n < 4; n++)
      bv[n] = *(bf16x8*)&Vt[(n * 16 + c) * PSTR + ks * 32 + g * 8];
#pragma unroll
    for (int m = 0; m < 2; m++)
#pragma unroll
      for (int n = 0; n < 4; n++)
        oacc[m][n] = __builtin_amdgcn_mfma_f32_16x16x32_bf16(ap[m], bv[n], oacc[m][n], 0, 0, 0);
  }

#pragma unroll
  for (int m = 0; m < 2; m++) {
    int rbase = w * 32 + m * 16 + g * 4;
#pragma unroll
    for (int n = 0; n < 4; n++) {
      int d = n * 16 + c;
#pragma unroll
      for (int j = 0; j < 4; j++) {
        int s = s0 + rbase + j;
        outa[(size_t)(b * N_S + s) * N_C + h * N_D + d] = f2b(oacc[m][n][j]);
      }
    }
  }
}

extern "C" void kernel_launch(void* const* d_in, const int* in_sizes, int n_in,
                              void* d_out, int out_size, void* d_ws, size_t ws_size,
                              hipStream_t stream) {
  const float* hs   = (const float*)d_in[0];
  const float* enc  = (const float*)d_in[1];
  const float* Wq   = (const float*)d_in[2];
  const float* Wk   = (const float*)d_in[3];
  const float* Wv   = (const float*)d_in[4];
  const float* Wkip = (const float*)d_in[5];
  const float* Wvip = (const float*)d_in[6];
  const float* Wklb = (const float*)d_in[7];
  const float* Wvlb = (const float*)d_in[8];
  const float* Wo   = (const float*)d_in[9];
  const float* bo   = (const float*)d_in[10];

  if (ws_size < 83087360u) return;
  char* ws = (char*)d_ws;
  u16* wq_t   = (u16*)(ws + 0);
  u16* wo_t   = (u16*)(ws + 3276800);
  u16* wk_t   = (u16*)(ws + 6553600);
  u16* wv_t   = (u16*)(ws + 11796480);
  u16* wkip_t = (u16*)(ws + 17039360);
  u16* wvip_t = (u16*)(ws + 22282240);
  u16* wklb_t = (u16*)(ws + 27525120);
  u16* wvlb_t = (u16*)(ws + 32768000);
  u16* etxt   = (u16*)(ws + 38010880);
  u16* eimg   = (u16*)(ws + 39272448);
  u16* elbl   = (u16*)(ws + 39337984);
  u16* ktxt   = (u16*)(ws + 39403520);
  u16* vtxt   = (u16*)(ws + 40192000);
  u16* kimg   = (u16*)(ws + 40980480);
  u16* vimg   = (u16*)(ws + 41021440);
  u16* klbl   = (u16*)(ws + 41062400);
  u16* vlbl   = (u16*)(ws + 41103360);
  u16* attn   = (u16*)(ws + 41144320);
  // d_out (84 MB): lower half = q bf16, upper half = hs bf16; both consumed
  // before the final O-proj overwrites d_out with f32 output.
  u16* qbuf   = (u16*)d_out;
  u16* hsb    = (u16*)d_out + (size_t)N_S * N_B * N_C;

  k_cvt<<<2048, 256, 0, stream>>>(hs, hsb, (N_B * N_S * N_C) / 8);

  TPargs tp;
  tp.s[0] = Wq;   tp.d[0] = wq_t;   tp.K[0] = 1280;
  tp.s[1] = Wo;   tp.d[1] = wo_t;   tp.K[1] = 1280;
  tp.s[2] = Wk;   tp.d[2] = wk_t;   tp.K[2] = 2048;
  tp.s[3] = Wv;   tp.d[3] = wv_t;   tp.K[3] = 2048;
  tp.s[4] = Wkip; tp.d[4] = wkip_t; tp.K[4] = 2048;
  tp.s[5] = Wvip; tp.d[5] = wvip_t; tp.K[5] = 2048;
  tp.s[6] = Wklb; tp.d[6] = wklb_t; tp.K[6] = 2048;
  tp.s[7] = Wvlb; tp.d[7] = wvlb_t; tp.K[7] = 2048;
  k_transpose8<<<dim3(40, 64, 8), dim3(32, 8), 0, stream>>>(tp);

  k_encpack<<<340, 256, 0, stream>>>(enc, etxt, eimg, elbl);

  // Q = hs @ Wq scaled by D^-0.5  (256x320 tiles, grid 256 = 1 full round)
  gemm8p<1><<<256, 512, 0, stream>>>(hsb, wq_t, qbuf, 16384, 1280, 1280,
                                     0.125f, nullptr, nullptr);
  // all 6 KV projections, one launch (prefetched 2-phase)
  kv_gemm<<<dim3(10, 5, 2), 256, 0, stream>>>(etxt, eimg, elbl,
                                              wk_t, wv_t, wkip_t, wvip_t, wklb_t, wvlb_t,
                                              ktxt, vtxt, kimg, vimg, klbl, vlbl);

  attn_kern<<<dim3(32, N_H, N_B), 256, 0, stream>>>(qbuf, ktxt, vtxt, kimg, vimg,
                                                    klbl, vlbl, attn);
  // out = attn @ Wo + bo + hs
  gemm8p<2><<<256, 512, 0, stream>>>(attn, wo_t, d_out, 16384, 1280, 1280,
                                     1.f, bo, hs);
}

// Round 6
// 257.680 us; speedup vs baseline: 2.3833x; 1.0341x over previous
//
#include <hip/hip_runtime.h>
#include <hip/hip_bf16.h>

typedef unsigned short u16;
using f32x4  = __attribute__((ext_vector_type(4))) float;
using bf16x8 = __attribute__((ext_vector_type(8))) short;

#define N_B 4
#define N_S 4096
#define N_C 1280
#define N_DC 2048
#define N_H 20
#define N_D 64

__device__ __forceinline__ u16 f2b(float f) {
  union { float f; unsigned u; } x; x.f = f;
  return (u16)((x.u + 0x7fffu + ((x.u >> 16) & 1u)) >> 16);
}

__device__ __forceinline__ void gld16(const u16* g, u16* l) {
  __builtin_amdgcn_global_load_lds(
      (const __attribute__((address_space(1))) unsigned int*)(g),
      (__attribute__((address_space(3))) unsigned int*)(l), 16, 0, 0);
}

// ---------- hs f32 -> bf16
__global__ void k_cvt(const float* __restrict__ src, u16* __restrict__ dst, int n8) {
  for (int i = blockIdx.x * 256 + threadIdx.x; i < n8; i += gridDim.x * 256) {
    const float4 v0 = *(const float4*)(src + (size_t)i * 8);
    const float4 v1 = *(const float4*)(src + (size_t)i * 8 + 4);
    alignas(16) u16 t[8];
    t[0] = f2b(v0.x); t[1] = f2b(v0.y); t[2] = f2b(v0.z); t[3] = f2b(v0.w);
    t[4] = f2b(v1.x); t[5] = f2b(v1.y); t[6] = f2b(v1.z); t[7] = f2b(v1.w);
    *(uint4*)(dst + (size_t)i * 8) = *(uint4*)t;
  }
}

// ---------- batched weight transpose + bf16
struct TPargs { const float* s[8]; u16* d[8]; int K[8]; };

__global__ void k_transpose8(TPargs a) {
  int z = blockIdx.z;
  const float* __restrict__ src = a.s[z];
  u16* __restrict__ dst = a.d[z];
  int K = a.K[z];
  int k0 = blockIdx.y * 32;
  if (k0 >= K) return;
  __shared__ float tl[32][33];
  int n0 = blockIdx.x * 32;
  int tx = threadIdx.x, ty = threadIdx.y;
#pragma unroll
  for (int j = 0; j < 32; j += 8)
    tl[ty + j][tx] = src[(size_t)(k0 + ty + j) * N_C + (n0 + tx)];
  __syncthreads();
#pragma unroll
  for (int j = 0; j < 32; j += 8)
    dst[(size_t)(n0 + ty + j) * K + (k0 + tx)] = f2b(tl[tx][ty + j]);
}

// ---------- pack encoder rows
__global__ void k_encpack(const float* __restrict__ enc, u16* __restrict__ txt,
                          u16* __restrict__ img, u16* __restrict__ lbl) {
  int row = blockIdx.x;
  int b = row / 85, l = row % 85;
  const float* s = enc + (size_t)row * N_DC;
  u16* d;
  if (l < 77)      d = txt + (size_t)(b * 77 + l) * N_DC;
  else if (l < 81) d = img + (size_t)(b * 4 + (l - 77)) * N_DC;
  else             d = lbl + (size_t)(b * 4 + (l - 81)) * N_DC;
  for (int i = threadIdx.x; i < N_DC; i += 256) d[i] = f2b(s[i]);
}

// ================= 256x320 GEMM, double-buffered, 1 barrier/K-tile ========
// C[M x N] = A[M x K](bf16) * Bt[N x K]^T.  512 thr = 8 waves (2M x 4N),
// wave tile 128x80, BK=64.
// LDS (u16 offsets): A0 [0,16384) A1 [16384,32768) B0 [32768,53248)
// B1 [53248,73728)  -> 144 KB.
// Grid = (M/256)*(N/320) = 256 blocks = exactly one full round on 256 CUs.
// Per K-tile: straight-line (no intra-tile barriers -- all phases read buf c,
// stage targets buf c^1, no hazard). Stage 9 loads issued first (T14), then
// RD-chunk/MFMA-cluster pairs with compiler-managed counted lgkmcnt; single
// vmcnt(0) + s_barrier at the tile boundary.
// EPI: 1 = bf16 store * scale, 2 = f32 store + bias + resid

__device__ __forceinline__ void stage64(const u16* __restrict__ g, int ldK,
                                        int row0, int kk, u16* ldsb,
                                        int w, int lane) {
  int r = w * 8 + (lane >> 3);
  int gslot = ((lane & 7) ^ (lane >> 3)) << 3;
  gld16(g + (size_t)(row0 + r) * ldK + kk + gslot, ldsb + w * 512);
}
__device__ __forceinline__ void stageA4(const u16* Ag, int K, int kk, u16* ldsb,
                                        int w, int lane) {
#pragma unroll
  for (int j = 0; j < 4; j++)
    stage64(Ag, K, j * 64, kk, ldsb + j * 4096, w, lane);
}
__device__ __forceinline__ void stageB5(const u16* Bg, int K, int kk, u16* ldsb,
                                        int w, int lane) {
#pragma unroll
  for (int j = 0; j < 5; j++)
    stage64(Bg, K, j * 64, kk, ldsb + j * 4096, w, lane);
}

#define RD_A2(aoff, mh)                                                      \
  _Pragma("unroll") for (int mi = 0; mi < 2; mi++) {                         \
    _Pragma("unroll") for (int ks = 0; ks < 2; ks++) {                       \
      int row = wr * 128 + ((mh) * 2 + mi) * 16 + lrow;                      \
      int slot = (ks * 4 + g) ^ (lane & 7);                                  \
      af[mi][ks] = *(const bf16x8*)&lds[(aoff) + row * 64 + slot * 8];       \
    }                                                                        \
  }

#define RD_B5(boff)                                                          \
  _Pragma("unroll") for (int n = 0; n < 5; n++) {                            \
    _Pragma("unroll") for (int ks = 0; ks < 2; ks++) {                       \
      int row = wc * 80 + n * 16 + lrow;                                     \
      int slot = (ks * 4 + g) ^ (lane & 7);                                  \
      bf[n][ks] = *(const bf16x8*)&lds[(boff) + row * 64 + slot * 8];        \
    }                                                                        \
  }

#define MFMA20(mh)                                                           \
  _Pragma("unroll") for (int mi = 0; mi < 2; mi++) {                         \
    _Pragma("unroll") for (int n = 0; n < 5; n++) {                          \
      _Pragma("unroll") for (int ks = 0; ks < 2; ks++)                       \
        acc[(mh) * 2 + mi][n] = __builtin_amdgcn_mfma_f32_16x16x32_bf16(     \
            af[mi][ks], bf[n][ks], acc[(mh) * 2 + mi][n], 0, 0, 0);          \
    }                                                                        \
  }

#define BARR()  __builtin_amdgcn_s_barrier()
#define VM0()   asm volatile("s_waitcnt vmcnt(0)" ::: "memory")
#define PRIO(x) __builtin_amdgcn_s_setprio(x)

template<int EPI>
__global__ __launch_bounds__(512, 1)
void gemm8p(const u16* __restrict__ A, const u16* __restrict__ Bt,
            void* __restrict__ Cv, int M, int N, int K, float scale,
            const float* __restrict__ bias, const float* __restrict__ resid) {
  __shared__ __align__(16) u16 lds[73728];
  const int t = threadIdx.x, lane = t & 63, w = t >> 6;
  const int wr = w >> 2, wc = w & 3;
  const int lrow = lane & 15, g = lane >> 4;

  int nt = N / 320;
  int nwg = gridDim.x, bid = blockIdx.x;
  int swz = ((nwg & 7) == 0) ? ((bid & 7) * (nwg >> 3) + (bid >> 3)) : bid;
  int bm = swz / nt, bn = swz % nt;

  const u16* Ag = A  + (size_t)bm * 256 * K;
  const u16* Bg = Bt + (size_t)bn * 320 * K;
  const int NT = K >> 6;

  f32x4 acc[8][5] = {};
  bf16x8 af[2][2], bf[5][2];

  // prologue: stage tile0 -> buf0
  stageA4(Ag, K, 0, lds + 0,     w, lane);
  stageB5(Bg, K, 0, lds + 32768, w, lane);
  VM0();
  BARR();

  for (int tt = 0; tt < NT; ++tt) {
    int c = tt & 1;
    int aof  = c * 16384,        bof  = 32768 + c * 20480;
    int aof1 = (c ^ 1) * 16384,  bof1 = 32768 + (c ^ 1) * 20480;
    // issue all 9 prefetch loads for tile t+1 first (uniform branch)
    if (tt + 1 < NT) {
      stageA4(Ag, K, (tt + 1) * 64, lds + aof1, w, lane);
      stageB5(Bg, K, (tt + 1) * 64, lds + bof1, w, lane);
    }
    // straight-line compute on buf c; compiler manages counted lgkmcnt
    RD_A2(aof, 0); RD_B5(bof);
    PRIO(1); MFMA20(0); PRIO(0);
    RD_A2(aof, 1);
    PRIO(1); MFMA20(1); PRIO(0);
    RD_A2(aof, 2);
    PRIO(1); MFMA20(2); PRIO(0);
    RD_A2(aof, 3);
    PRIO(1); MFMA20(3); PRIO(0);
    // tile boundary: next tile's buf fully staged, all readers of c done
    VM0();
    BARR();
  }

  // epilogue
#pragma unroll
  for (int m = 0; m < 8; m++) {
    int row = bm * 256 + wr * 128 + m * 16 + g * 4;
#pragma unroll
    for (int n = 0; n < 5; n++) {
      int col = bn * 320 + wc * 80 + n * 16 + lrow;
#pragma unroll
      for (int j = 0; j < 4; j++) {
        float v = acc[m][n][j];
        if constexpr (EPI == 1)
          ((u16*)Cv)[(size_t)(row + j) * N + col] = f2b(v * scale);
        else
          ((float*)Cv)[(size_t)(row + j) * N + col] =
              v + bias[col] + resid[(size_t)(row + j) * N + col];
      }
    }
  }
}

// ---------- all 6 KV projections in one launch, prefetched 2-phase
__global__ __launch_bounds__(256, 2)
void kv_gemm(const u16* __restrict__ etxt, const u16* __restrict__ eimg, const u16* __restrict__ elbl,
             const u16* __restrict__ wk,   const u16* __restrict__ wv,
             const u16* __restrict__ wkip, const u16* __restrict__ wvip,
             const u16* __restrict__ wklb, const u16* __restrict__ wvlb,
             u16* ktxt, u16* vtxt, u16* kimg, u16* vimg, u16* klbl, u16* vlbl) {
  __shared__ __align__(16) u16 lds[2][2][8192];   // [buf][A/B][128*64]
  int bn = blockIdx.x, my = blockIdx.y, kv = blockIdx.z;
  const u16 *A, *Bt; u16* C; int M, bm;
  if (my < 3)       { A = etxt; M = 308; bm = my; Bt = kv ? wv   : wk;   C = kv ? vtxt : ktxt; }
  else if (my == 3) { A = eimg; M = 16;  bm = 0;  Bt = kv ? wvip : wkip; C = kv ? vimg : kimg; }
  else              { A = elbl; M = 16;  bm = 0;  Bt = kv ? wvlb : wklb; C = kv ? vlbl : klbl; }
  const int K = 2048;
  int t = threadIdx.x, lane = t & 63, w = t >> 6;
  int wm = w >> 1, wn = w & 1;
  int c8 = lane & 7, rsub = lane >> 3;

  f32x4 acc[4][4] = {};

#define KVSTAGE(kt, buf)                                                      \
  {                                                                           \
    int k0 = (kt) * 64;                                                       \
    _Pragma("unroll") for (int i2 = 0; i2 < 4; i2++) {                        \
      int rloc = w * 32 + i2 * 8;                                             \
      int ra = bm * 128 + rloc + rsub; if (ra >= M) ra = M - 1;               \
      int rb = bn * 128 + rloc + rsub;                                        \
      gld16(A  + (size_t)ra * K + k0 + c8 * 8, &lds[buf][0][rloc * 64]);      \
      gld16(Bt + (size_t)rb * K + k0 + c8 * 8, &lds[buf][1][rloc * 64]);      \
    }                                                                         \
  }

  KVSTAGE(0, 0);
  asm volatile("s_waitcnt vmcnt(0)" ::: "memory");
  __syncthreads();
  int cur = 0;
  for (int kt = 0; kt < 32; kt++) {
    if (kt < 31) KVSTAGE(kt + 1, cur ^ 1);
#pragma unroll
    for (int ks = 0; ks < 2; ks++) {
      bf16x8 afr[4], bfr[4];
#pragma unroll
      for (int m = 0; m < 4; m++)
        afr[m] = *(bf16x8*)&lds[cur][0][(wm * 64 + m * 16 + (lane & 15)) * 64 + ks * 32 + (lane >> 4) * 8];
#pragma unroll
      for (int n = 0; n < 4; n++)
        bfr[n] = *(bf16x8*)&lds[cur][1][(wn * 64 + n * 16 + (lane & 15)) * 64 + ks * 32 + (lane >> 4) * 8];
#pragma unroll
      for (int m = 0; m < 4; m++)
#pragma unroll
        for (int n = 0; n < 4; n++)
          acc[m][n] = __builtin_amdgcn_mfma_f32_16x16x32_bf16(afr[m], bfr[n], acc[m][n], 0, 0, 0);
    }
    asm volatile("s_waitcnt vmcnt(0)" ::: "memory");
    __syncthreads();
    cur ^= 1;
  }
#undef KVSTAGE

#pragma unroll
  for (int m = 0; m < 4; m++) {
    int row = bm * 128 + wm * 64 + m * 16 + ((lane >> 4) << 2);
#pragma unroll
    for (int n = 0; n < 4; n++) {
      int col = bn * 128 + wn * 64 + n * 16 + (lane & 15);
#pragma unroll
      for (int j = 0; j < 4; j++) {
        int r = row + j;
        if (r >= M) continue;
        ((u16*)C)[(size_t)r * 1280 + col] = f2b(acc[m][n][j]);
      }
    }
  }
}

// ---------- fused attention (unchanged)
#define QSTR 72
#define PSTR 104

__global__ __launch_bounds__(256, 2)
void attn_kern(const u16* __restrict__ q,
               const u16* __restrict__ ktxt, const u16* __restrict__ vtxt,
               const u16* __restrict__ kimg, const u16* __restrict__ vimg,
               const u16* __restrict__ klbl, const u16* __restrict__ vlbl,
               u16* __restrict__ outa) {
  __shared__ __align__(16) char smem[45568];
  u16* Qs = (u16*)smem;
  u16* Ks = (u16*)(smem + 18432);
  u16* Ps = (u16*)smem;
  u16* Vt = (u16*)(smem + 32256);

  int st = blockIdx.x, h = blockIdx.y, b = blockIdx.z;
  int t = threadIdx.x, lane = t & 63, w = t >> 6;
  int s0 = st * 128;
  int c = lane & 15, g = lane >> 4;

  for (int i = t; i < 27136 / 16; i += 256)
    ((uint4*)(smem + 18432))[i] = make_uint4(0, 0, 0, 0);
#pragma unroll
  for (int i = 0; i < 4; i++) {
    int cid = t + i * 256; int r = cid >> 3, c8 = cid & 7;
    *(uint4*)&Qs[r * QSTR + c8 * 8] =
        *(const uint4*)(q + (size_t)(b * N_S + s0 + r) * N_C + h * N_D + c8 * 8);
  }
  __syncthreads();
  for (int cid = t; cid < 680; cid += 256) {
    int l = cid >> 3, c8 = cid & 7;
    const u16* p;
    if (l < 77)      p = ktxt + (size_t)(b * 77 + l) * N_C + h * N_D + c8 * 8;
    else if (l < 81) p = kimg + (size_t)(b * 4 + l - 77) * N_C + h * N_D + c8 * 8;
    else             p = klbl + (size_t)(b * 4 + l - 81) * N_C + h * N_D + c8 * 8;
    int row = (l < 77) ? l : l + 3;
    *(uint4*)&Ks[row * QSTR + c8 * 8] = *(const uint4*)p;
  }
  for (int e = t; e < 85 * 64; e += 256) {
    int l = e >> 6, d = e & 63;
    const u16* p;
    if (l < 77)      p = vtxt + (size_t)(b * 77 + l) * N_C + h * N_D + d;
    else if (l < 81) p = vimg + (size_t)(b * 4 + l - 77) * N_C + h * N_D + d;
    else             p = vlbl + (size_t)(b * 4 + l - 81) * N_C + h * N_D + d;
    int slot = (l < 77) ? l : l + 3;
    Vt[d * PSTR + slot] = *p;
  }
  __syncthreads();

  f32x4 sacc[2][6] = {};
#pragma unroll
  for (int ks = 0; ks < 2; ks++) {
    bf16x8 aq[2], bk[6];
#pragma unroll
    for (int m = 0; m < 2; m++)
      aq[m] = *(bf16x8*)&Qs[(w * 32 + m * 16 + c) * QSTR + ks * 32 + g * 8];
#pragma unroll
    for (int n = 0; n < 6; n++)
      bk[n] = *(bf16x8*)&Ks[(n * 16 + c) * QSTR + ks * 32 + g * 8];
#pragma unroll
    for (int m = 0; m < 2; m++)
#pragma unroll
      for (int n = 0; n < 6; n++)
        sacc[m][n] = __builtin_amdgcn_mfma_f32_16x16x32_bf16(aq[m], bk[n], sacc[m][n], 0, 0, 0);
  }
  __syncthreads();

  const float NEG = -1e30f;
#pragma unroll
  for (int m = 0; m < 2; m++) {
#pragma unroll
    for (int j = 0; j < 4; j++) {
      float tmax = NEG;
#pragma unroll
      for (int n = 0; n < 5; n++)
        if (n * 16 + c < 77) tmax = fmaxf(tmax, sacc[m][n][j]);
#pragma unroll
      for (int off = 1; off < 16; off <<= 1) tmax = fmaxf(tmax, __shfl_xor(tmax, off));
      float pv[5], tsum = 0.f;
#pragma unroll
      for (int n = 0; n < 5; n++) {
        float v = (n * 16 + c < 77) ? __expf(sacc[m][n][j] - tmax) : 0.f;
        pv[n] = v; tsum += v;
      }
#pragma unroll
      for (int off = 1; off < 16; off <<= 1) tsum += __shfl_xor(tsum, off);
      float v5 = sacc[m][5][j];
      float imax = (c < 4) ? v5 : NEG;
#pragma unroll
      for (int off = 1; off < 16; off <<= 1) imax = fmaxf(imax, __shfl_xor(imax, off));
      float ie = (c < 4) ? __expf(v5 - imax) : 0.f, isum = ie;
#pragma unroll
      for (int off = 1; off < 16; off <<= 1) isum += __shfl_xor(isum, off);
      float lmax = (c >= 4 && c < 8) ? v5 : NEG;
#pragma unroll
      for (int off = 1; off < 16; off <<= 1) lmax = fmaxf(lmax, __shfl_xor(lmax, off));
      float le = (c >= 4 && c < 8) ? __expf(v5 - lmax) : 0.f, lsum = le;
#pragma unroll
      for (int off = 1; off < 16; off <<= 1) lsum += __shfl_xor(lsum, off);

      float rt = 1.f / tsum;
      float p5 = (c < 4) ? ie / isum : ((c < 8) ? le / lsum : 0.f);
      int rowl = w * 32 + m * 16 + g * 4 + j;
#pragma unroll
      for (int n = 0; n < 5; n++)
        Ps[rowl * PSTR + n * 16 + c] = f2b(pv[n] * rt);
      Ps[rowl * PSTR + 80 + c] = f2b(p5);
    }
  }
  __syncthreads();

  f32x4 oacc[2][4] = {};
#pragma unroll
  for (int ks = 0; ks < 3; ks++) {
    bf16x8 ap[2], bv[4];
#pragma unroll
    for (int m = 0; m < 2; m++)
      ap[m] = *(bf16x8*)&Ps[(w * 32 + m * 16 + c) * PSTR + ks * 32 + g * 8];
#pragma unroll
    for (int n = 0; n < 4; n++)
      bv[n] = *(bf16x8*)&Vt[(n * 16 + c) * PSTR + ks * 32 + g * 8];
#pragma unroll
    for (int m = 0; m < 2; m++)
#pragma unroll
      for (int n = 0; n < 4; n++)
        oacc[m][n] = __builtin_amdgcn_mfma_f32_16x16x32_bf16(ap[m], bv[n], oacc[m][n], 0, 0, 0);
  }

#pragma unroll
  for (int m = 0; m < 2; m++) {
    int rbase = w * 32 + m * 16 + g * 4;
#pragma unroll
    for (int n = 0; n < 4; n++) {
      int d = n * 16 + c;
#pragma unroll
      for (int j = 0; j < 4; j++) {
        int s = s0 + rbase + j;
        outa[(size_t)(b * N_S + s) * N_C + h * N_D + d] = f2b(oacc[m][n][j]);
      }
    }
  }
}

extern "C" void kernel_launch(void* const* d_in, const int* in_sizes, int n_in,
                              void* d_out, int out_size, void* d_ws, size_t ws_size,
                              hipStream_t stream) {
  const float* hs   = (const float*)d_in[0];
  const float* enc  = (const float*)d_in[1];
  const float* Wq   = (const float*)d_in[2];
  const float* Wk   = (const float*)d_in[3];
  const float* Wv   = (const float*)d_in[4];
  const float* Wkip = (const float*)d_in[5];
  const float* Wvip = (const float*)d_in[6];
  const float* Wklb = (const float*)d_in[7];
  const float* Wvlb = (const float*)d_in[8];
  const float* Wo   = (const float*)d_in[9];
  const float* bo   = (const float*)d_in[10];

  if (ws_size < 83087360u) return;
  char* ws = (char*)d_ws;
  u16* wq_t   = (u16*)(ws + 0);
  u16* wo_t   = (u16*)(ws + 3276800);
  u16* wk_t   = (u16*)(ws + 6553600);
  u16* wv_t   = (u16*)(ws + 11796480);
  u16* wkip_t = (u16*)(ws + 17039360);
  u16* wvip_t = (u16*)(ws + 22282240);
  u16* wklb_t = (u16*)(ws + 27525120);
  u16* wvlb_t = (u16*)(ws + 32768000);
  u16* etxt   = (u16*)(ws + 38010880);
  u16* eimg   = (u16*)(ws + 39272448);
  u16* elbl   = (u16*)(ws + 39337984);
  u16* ktxt   = (u16*)(ws + 39403520);
  u16* vtxt   = (u16*)(ws + 40192000);
  u16* kimg   = (u16*)(ws + 40980480);
  u16* vimg   = (u16*)(ws + 41021440);
  u16* klbl   = (u16*)(ws + 41062400);
  u16* vlbl   = (u16*)(ws + 41103360);
  u16* attn   = (u16*)(ws + 41144320);
  // d_out (84 MB): lower half = q bf16, upper half = hs bf16; both consumed
  // before the final O-proj overwrites d_out with f32 output.
  u16* qbuf   = (u16*)d_out;
  u16* hsb    = (u16*)d_out + (size_t)N_S * N_B * N_C;

  k_cvt<<<2048, 256, 0, stream>>>(hs, hsb, (N_B * N_S * N_C) / 8);

  TPargs tp;
  tp.s[0] = Wq;   tp.d[0] = wq_t;   tp.K[0] = 1280;
  tp.s[1] = Wo;   tp.d[1] = wo_t;   tp.K[1] = 1280;
  tp.s[2] = Wk;   tp.d[2] = wk_t;   tp.K[2] = 2048;
  tp.s[3] = Wv;   tp.d[3] = wv_t;   tp.K[3] = 2048;
  tp.s[4] = Wkip; tp.d[4] = wkip_t; tp.K[4] = 2048;
  tp.s[5] = Wvip; tp.d[5] = wvip_t; tp.K[5] = 2048;
  tp.s[6] = Wklb; tp.d[6] = wklb_t; tp.K[6] = 2048;
  tp.s[7] = Wvlb; tp.d[7] = wvlb_t; tp.K[7] = 2048;
  k_transpose8<<<dim3(40, 64, 8), dim3(32, 8), 0, stream>>>(tp);

  k_encpack<<<340, 256, 0, stream>>>(enc, etxt, eimg, elbl);

  // Q = hs @ Wq scaled by D^-0.5  (256x320 tiles, grid 256 = 1 full round)
  gemm8p<1><<<256, 512, 0, stream>>>(hsb, wq_t, qbuf, 16384, 1280, 1280,
                                     0.125f, nullptr, nullptr);
  // all 6 KV projections, one launch (prefetched 2-phase)
  kv_gemm<<<dim3(10, 5, 2), 256, 0, stream>>>(etxt, eimg, elbl,
                                              wk_t, wv_t, wkip_t, wvip_t, wklb_t, wvlb_t,
                                              ktxt, vtxt, kimg, vimg, klbl, vlbl);

  attn_kern<<<dim3(32, N_H, N_B), 256, 0, stream>>>(qbuf, ktxt, vtxt, kimg, vimg,
                                                    klbl, vlbl, attn);
  // out = attn @ Wo + bo + hs
  gemm8p<2><<<256, 512, 0, stream>>>(attn, wo_t, d_out, 16384, 1280, 1280,
                                     1.f, bo, hs);
}